// Round 5
// baseline (241.983 us; speedup 1.0000x reference)
//
#include <hip/hip_runtime.h>
#include <hip/hip_bf16.h>

// B=4, S=2048, D=1024. x:[4,2048,1024] f32; wq/wk/wv:[1024,1024] f32.
// out:[4,2048,1024] f32.
//
// Pipeline (bf16 MFMA, fp32 accum):
//   1. convx:  x f32 -> xb bf16                        [8192,1024]
//   2. wtrans: wq/wk/wv f32 -> wt bf16 TRANSPOSED      [3][1024(n)][1024(k)]
//   3. gemm256<0>: qb,kb = xb @ wt[0:2]^T (N=2048 fused), bf16 out
//   4. gemm256<3>: vt = wt[2] @ xb^T  -> [4][1024(d)][2048(s)] bf16
//   5. gemm256<1>: scores = (qb @ kb^T)/32, causal block-skip, f32 out
//   6. softmax: causal row softmax, bf16 attn in-place, zero-pad to 256-edge
//   7. gemm256<2>: out = attn @ vt^T (Kend = m0+256), f32 out
//
// R5 (derived-waits schedule): two latency-exposure fixes vs R4:
//  (a) all 8 staging loads issued in one burst at iteration TOP (3+ phases
//      of latency cover); tile-ready wait is vmcnt(0) at phase 3, by then
//      normally satisfied.
//  (b) each phase issues the NEXT phase's ds_reads and waits a COUNTED
//      lgkmcnt (4 or 8), so this phase's MFMA overlaps next phase's LDS
//      reads. Count proof: at each wait, outstanding = prev-phase frags
//      (4 or 8, being waited) + just-issued (4 or 8, left in flight).
//      p0: 8old+4new -> lgkm(4); p1: 4+8 -> lgkm(8); p2: 8+4 -> lgkm(4);
//      p3: 4+8(next-tile reads, after vmcnt(0)+barrier) -> lgkm(8).
// sched_barrier(0) after every counted wait (rule #18: hipcc hoists
// register-only MFMA past inline-asm waitcnt otherwise).

typedef __attribute__((ext_vector_type(8))) short bf16x8;
typedef __attribute__((ext_vector_type(4))) float f32x4;

#define GLOAD_LDS16(g, l)                                                     \
    __builtin_amdgcn_global_load_lds(                                         \
        (const __attribute__((address_space(1))) void*)(g),                   \
        (__attribute__((address_space(3))) void*)(l), 16, 0, 0)

__device__ __forceinline__ short f2bf(float f) {
    union { float f; unsigned u; } v; v.f = f;
    unsigned r = v.u + 0x7FFFu + ((v.u >> 16) & 1u);
    return (short)(r >> 16);
}

// ---------------- convert x to bf16 ----------------
__global__ __launch_bounds__(256) void convx(const float* __restrict__ x,
                                             short* __restrict__ xb, int n4) {
    int i = blockIdx.x * 256 + threadIdx.x;
    if (i < n4) {
        float4 v = ((const float4*)x)[i];
        short4 o;
        o.x = f2bf(v.x); o.y = f2bf(v.y); o.z = f2bf(v.z); o.w = f2bf(v.w);
        ((short4*)xb)[i] = o;
    }
}

// ---------------- weights: f32 [k][n] -> bf16 [n][k] ----------------
__global__ __launch_bounds__(256) void wtrans(const float* __restrict__ wq,
                                              const float* __restrict__ wk,
                                              const float* __restrict__ wv,
                                              short* __restrict__ wt) {
    int w = blockIdx.z;
    const float* W = (w == 0) ? wq : (w == 1) ? wk : wv;
    short* O = wt + (size_t)w * 1048576;
    int n0 = blockIdx.x * 64, k0 = blockIdx.y * 64;
    __shared__ float tile[64][65];
    int t = threadIdx.x;
#pragma unroll
    for (int i = 0; i < 16; ++i) {
        int idx = t + i * 256;
        int r = idx >> 6, c = idx & 63;
        tile[r][c] = W[(size_t)(k0 + r) * 1024 + n0 + c];
    }
    __syncthreads();
#pragma unroll
    for (int i = 0; i < 16; ++i) {
        int idx = t + i * 256;
        int r = idx >> 6, c = idx & 63;
        O[(size_t)(n0 + r) * 1024 + k0 + c] = f2bf(tile[c][r]);
    }
}

// ---------------- 256x256 NT GEMM, derived-waits 8-phase ----------------
// C[m][n] = sum_k A[m][k] * B[n][k]
template <int MODE>
__global__ __launch_bounds__(512, 2) void gemm256(
    const short* __restrict__ A0, int lda, long long sA,
    const short* __restrict__ B0, int ldb, long long sB,
    void* __restrict__ C0, float scale) {

    const int m0 = blockIdx.y * 256;
    const int n0 = blockIdx.x * 256;
    if (MODE == 1 && n0 > m0 + 255) return;  // fully above diagonal
    const int z = blockIdx.z;
    const short* Ab = A0 + (size_t)z * sA;
    const short* Bb = B0 + (size_t)z * sB;

    const int tid = threadIdx.x;
    const int lane = tid & 63;
    const int wid = tid >> 6;
    const int wm = wid >> 2, wn = wid & 3;  // 2x4 waves, wave tile 128x64

    // [buf][half][128 rows x 64 cols] bf16; 128 KiB total.
    __shared__ __align__(16) short As[2][2][8192];
    __shared__ __align__(16) short Bs[2][2][8192];

    f32x4 acc[8][4] = {};

    const int Kend = (MODE == 2) ? (m0 + 256) : 1024;
    const int nt = Kend >> 6;  // >= 4

    // staging: 8 thr/row x 16B; physical slot (tid&7) holds logical slot
    // (tid&7)^(row&7): pre-swizzled global source, linear LDS dest.
    const int srow = tid >> 3;
    const int sl = (tid & 7) ^ (srow & 7);
    const short* Agp = Ab + (size_t)(m0 + srow) * lda + sl * 8;
    const short* Bgp = Bb + (size_t)(n0 + srow) * ldb + sl * 8;

#define SA(kt, bf, h)                                                         \
    do {                                                                      \
        const int _k = (kt) << 6;                                             \
        GLOAD_LDS16(Agp + _k + (size_t)((h)*128 + 0) * lda,                   \
                    &As[bf][h][tid * 8]);                                     \
        GLOAD_LDS16(Agp + _k + (size_t)((h)*128 + 64) * lda,                  \
                    &As[bf][h][4096 + tid * 8]);                              \
    } while (0)
#define SB(kt, bf, h)                                                         \
    do {                                                                      \
        const int _k = (kt) << 6;                                             \
        GLOAD_LDS16(Bgp + _k + (size_t)((h)*128 + 0) * ldb,                   \
                    &Bs[bf][h][tid * 8]);                                     \
        GLOAD_LDS16(Bgp + _k + (size_t)((h)*128 + 64) * ldb,                  \
                    &Bs[bf][h][4096 + tid * 8]);                              \
    } while (0)
#define G8(kt, bf)                                                            \
    do { SA(kt, bf, 0); SA(kt, bf, 1); SB(kt, bf, 0); SB(kt, bf, 1); } while (0)

    const int r = lane & 15;
    const int g = lane >> 4;
    const int pxor = r & 7;

#define LDA4(dst, bf, mh, kk)                                                 \
    _Pragma("unroll") for (int q = 0; q < 4; ++q)                             \
        dst[q] = *(const bf16x8*)&As[bf][wm][((mh)*64 + q * 16 + r) * 64 +    \
                                             (((kk)*4 + g) ^ pxor) * 8];
#define LDB4(dst, bf, kk)                                                     \
    _Pragma("unroll") for (int q = 0; q < 4; ++q)                             \
        dst[q] = *(const bf16x8*)&Bs[bf][wn >> 1][((wn & 1) * 64 + q * 16 +   \
                                                   r) * 64 +                  \
                                                  (((kk)*4 + g) ^ pxor) * 8];
#define LGKM(n)                                                               \
    asm volatile("s_waitcnt lgkmcnt(" #n ")" ::: "memory");                   \
    __builtin_amdgcn_sched_barrier(0)
#define VM0() asm volatile("s_waitcnt vmcnt(0)" ::: "memory")
#define BAR() __builtin_amdgcn_s_barrier()
#define MF16(mh, ar, br)                                                      \
    do {                                                                      \
        __builtin_amdgcn_s_setprio(1);                                        \
        _Pragma("unroll") for (int q = 0; q < 4; ++q)                         \
            _Pragma("unroll") for (int ni = 0; ni < 4; ++ni)                  \
                acc[(mh)*4 + q][ni] = __builtin_amdgcn_mfma_f32_16x16x32_bf16(\
                    ar[q], br[ni], acc[(mh)*4 + q][ni], 0, 0, 0);             \
        __builtin_amdgcn_s_setprio(0);                                        \
    } while (0)

    bf16x8 aX[4], aY[4], aZ[4], aU[4], bX[4], bW[4];

    // prologue: stage tile 0, then issue phase-0 fragment reads
    G8(0, 0);
    VM0();
    BAR();
    LDA4(aX, 0, 0, 0); LDB4(bX, 0, 0);   // R0 of tile 0 (8 ds_reads in flight)

    int buf = 0;
    for (int t = 0; t < nt - 1; ++t) {
        const int nb = buf ^ 1;
        G8(t + 1, nb);  // burst all 8 staging loads: 3+ phases of cover
        // p0: MFMA(mh0,kk0) on aX,bX; prefetch R1
        LDA4(aY, buf, 1, 0);
        BAR();
        LGKM(4);        // R0 done, R1(4) in flight
        MF16(0, aX, bX);
        BAR();
        // p1: MFMA(mh1,kk0) on aY,bX; prefetch R2
        LDA4(aZ, buf, 0, 1); LDB4(bW, buf, 1);
        BAR();
        LGKM(8);        // R1 done, R2(8) in flight
        MF16(1, aY, bX);
        BAR();
        // p2: MFMA(mh0,kk1) on aZ,bW; prefetch R3
        LDA4(aU, buf, 1, 1);
        BAR();
        LGKM(4);        // R2 done, R3(4) in flight
        MF16(0, aZ, bW);
        BAR();
        // p3: tile t+1 ready; issue next tile's R0; MFMA(mh1,kk1)
        VM0();          // staging issued 3 phases ago — normally satisfied
        BAR();          // ALL waves' slices of tile t+1 now visible
        LDA4(aX, nb, 0, 0); LDB4(bX, nb, 0);
        LGKM(8);        // R3 done, next-R0(8) in flight
        MF16(1, aU, bW);
        BAR();
        buf = nb;
    }
    // peeled last tile (no staging, no successor reads)
    LDA4(aY, buf, 1, 0);
    BAR();
    LGKM(4);
    MF16(0, aX, bX);
    BAR();
    LDA4(aZ, buf, 0, 1); LDB4(bW, buf, 1);
    BAR();
    LGKM(8);
    MF16(1, aY, bX);
    BAR();
    LDA4(aU, buf, 1, 1);
    BAR();
    LGKM(4);
    MF16(0, aZ, bW);
    BAR();
    LGKM(0);
    MF16(1, aU, bW);

    // ---- C epilogue: C/D layout col=lane&15, row=(lane>>4)*4+reg
    const int r4 = (lane >> 4) * 4;
#pragma unroll
    for (int mi = 0; mi < 8; ++mi) {
#pragma unroll
        for (int ni = 0; ni < 4; ++ni) {
            int col = n0 + wn * 64 + ni * 16 + r;
#pragma unroll
            for (int i = 0; i < 4; ++i) {
                int rr = m0 + wm * 128 + mi * 16 + r4 + i;
                float v = acc[mi][ni][i];
                if (MODE == 0) {
                    ((short*)C0)[(size_t)(col >> 10) * 8388608 +
                                 (size_t)rr * 1024 + (col & 1023)] = f2bf(v);
                } else if (MODE == 3) {
                    ((short*)C0)[(size_t)(col >> 11) * 2097152 +
                                 (size_t)rr * 2048 + (col & 2047)] = f2bf(v);
                } else if (MODE == 1) {
                    if (col <= rr)
                        ((float*)C0)[(size_t)z * 4194304 +
                                     (size_t)rr * 2048 + col] = v * scale;
                } else {
                    ((float*)C0)[(size_t)z * 2097152 +
                                 (size_t)rr * 1024 + col] = v;
                }
            }
        }
    }
#undef SA
#undef SB
#undef G8
#undef LDA4
#undef LDB4
#undef LGKM
#undef VM0
#undef BAR
#undef MF16
}

// ---------------- causal row softmax, f32 scores -> bf16 attn in-place ------
__global__ __launch_bounds__(256) void softmax_causal(float* __restrict__ scores) {
    int row = blockIdx.x;            // 0..8191
    int b = row >> 11, i = row & 2047;
    float* srow = scores + ((size_t)b * 2048 + i) * 2048;
    short* arow = (short*)srow;      // bf16 written over the same row
    __shared__ float sv[2048];
    __shared__ float red[8];
    int t = threadIdx.x;
    int L = i + 1;

    float mx = -1e30f;
    for (int j = t; j < L; j += 256) {
        float v = srow[j];
        sv[j] = v;
        mx = fmaxf(mx, v);
    }
#pragma unroll
    for (int o = 32; o > 0; o >>= 1) mx = fmaxf(mx, __shfl_down(mx, o));
    if ((t & 63) == 0) red[t >> 6] = mx;
    __syncthreads();
    mx = fmaxf(fmaxf(red[0], red[1]), fmaxf(red[2], red[3]));

    float sum = 0.f;
    for (int j = t; j < L; j += 256) {
        float e = __expf(sv[j] - mx);
        sv[j] = e;
        sum += e;
    }
#pragma unroll
    for (int o = 32; o > 0; o >>= 1) sum += __shfl_down(sum, o);
    if ((t & 63) == 0) red[4 + (t >> 6)] = sum;
    __syncthreads();
    sum = red[4] + red[5] + red[6] + red[7];
    float rinv = 1.0f / sum;

    int Lpad = (i | 255) + 1;  // zero-fill to the 256-block edge for PV
    for (int j = t; j < Lpad; j += 256) {
        float p = (j < L) ? sv[j] * rinv : 0.0f;
        arow[j] = f2bf(p);
    }
}

extern "C" void kernel_launch(void* const* d_in, const int* in_sizes, int n_in,
                              void* d_out, int out_size, void* d_ws, size_t ws_size,
                              hipStream_t stream) {
    const float* x  = (const float*)d_in[0];
    const float* wq = (const float*)d_in[1];
    const float* wk = (const float*)d_in[2];
    const float* wv = (const float*)d_in[3];
    float* out = (float*)d_out;

    // workspace layout (shorts)
    short* ws16 = (short*)d_ws;
    short* xb = ws16;                    //  8,388,608 shorts
    short* wt = xb + 8388608;            //  3,145,728  [3][1024][1024]
    short* qb = wt + 3145728;            //  8,388,608  (kb must follow qb!)
    short* kb = qb + 8388608;            //  8,388,608
    short* vt = kb + 8388608;            //  8,388,608  [4][1024][2048]
    float* scores = (float*)(vt + 8388608);  // 4*2048*2048 f32

    convx<<<8192, 256, 0, stream>>>(x, xb, 2097152);
    wtrans<<<dim3(16, 16, 3), 256, 0, stream>>>(wq, wk, wv, wt);
    // Q,K fused: [8192 x 2048] = xb @ [wq^T;wk^T]^T
    gemm256<0><<<dim3(8, 32, 1), 512, 0, stream>>>(
        xb, 1024, 0LL, wt, 1024, 0LL, qb, 1.0f);
    // V^T: [1024 x 8192] = wt[v] @ xb^T
    gemm256<3><<<dim3(32, 4, 1), 512, 0, stream>>>(
        wt + 2097152, 1024, 0LL, xb, 1024, 0LL, vt, 1.0f);
    // scores = (q @ k^T)/32, causal
    gemm256<1><<<dim3(8, 8, 4), 512, 0, stream>>>(
        qb, 1024, 2097152LL, kb, 1024, 2097152LL, scores, 0.03125f);
    softmax_causal<<<8192, 256, 0, stream>>>(scores);
    // out = attn @ vt^T, Kend = m0+256
    gemm256<2><<<dim3(4, 8, 4), 512, 0, stream>>>(
        (const short*)scores, 4096, 8388608LL, vt, 2048, 2097152LL, out, 1.0f);
}

// Round 6
// 235.072 us; speedup vs baseline: 1.0294x; 1.0294x over previous
//
#include <hip/hip_runtime.h>
#include <hip/hip_bf16.h>

// B=4, S=2048, D=1024. x:[4,2048,1024] f32; wq/wk/wv:[1024,1024] f32.
// out:[4,2048,1024] f32.
//
// Pipeline (bf16 MFMA, fp32 accum):
//   1. convx:  x f32 -> xb bf16                        [8192,1024]
//   2. wtrans: wq/wk/wv f32 -> wt bf16 TRANSPOSED      [3][1024(n)][1024(k)]
//   3. gemm256<0>: qb,kb = xb @ wt[0:2]^T (N=2048 fused), bf16 out
//   4. gemm256<1>: MERGED dispatch: z<4 -> scores=(q@k^T)/32 causal;
//                  z=4,5 -> vt = wt[2] @ xb^T (fills the half-idle machine)
//   5. softmax: causal row softmax, bf16 attn in-place, zero-pad to 256-edge
//   6. gemm256<2>: out = attn @ vt^T (Kend = m0+256), f32 out
//
// R6 schedule (staging-depth fix): LDS regrouped by K-HALF:
//   As[buf][kh][256 rows x 32 shorts], Bs same (128 KiB total).
//   Tile t's 4 phases (kh,mh) stage tile t+1's half-tiles in consumption
//   order: A-k0@p0, B-k0@p1, A-k1@p2, B-k1@p3 (2 gload_lds each).
//   Waits: vmcnt(4) at p1-end (k1(t) ready — issued LAST tile, 4 phases
//   cover) and vmcnt(4) at p3-end (k0(t+1) ready — issued 3 phases ago;
//   leaves k1(t+1)'s 4 loads in flight). NEVER vmcnt(0) in-loop.
//   Only 2 barriers per K-tile (phases of a tile only READ the active
//   buffer; stages write the other buffer; anti-deps covered by the
//   boundary barrier).
// Reader swizzle: row stride is 64 B, so 16-lane groups alternate 0/64 mod
//   128B by row parity; physical 16B-slot = g ^ ((row>>1)&3) makes the 8
//   same-parity rows cover all four slots twice => exactly 2-way (free).
//   Writer pre-swizzles the global source: sl4 = (tid&3)^((tid>>3)&3)
//   (row=tid>>2; +128 rows leaves (row>>1)&3 unchanged).
// Plus T1 XCD-swizzle on block indices (all grids %8==0).

typedef __attribute__((ext_vector_type(8))) short bf16x8;
typedef __attribute__((ext_vector_type(4))) float f32x4;

#define GLOAD_LDS16(g, l)                                                     \
    __builtin_amdgcn_global_load_lds(                                         \
        (const __attribute__((address_space(1))) void*)(g),                   \
        (__attribute__((address_space(3))) void*)(l), 16, 0, 0)

__device__ __forceinline__ short f2bf(float f) {
    union { float f; unsigned u; } v; v.f = f;
    unsigned r = v.u + 0x7FFFu + ((v.u >> 16) & 1u);
    return (short)(r >> 16);
}

// ---------------- convert x to bf16 ----------------
__global__ __launch_bounds__(256) void convx(const float* __restrict__ x,
                                             short* __restrict__ xb, int n4) {
    int i = blockIdx.x * 256 + threadIdx.x;
    if (i < n4) {
        float4 v = ((const float4*)x)[i];
        short4 o;
        o.x = f2bf(v.x); o.y = f2bf(v.y); o.z = f2bf(v.z); o.w = f2bf(v.w);
        ((short4*)xb)[i] = o;
    }
}

// ---------------- weights: f32 [k][n] -> bf16 [n][k] ----------------
__global__ __launch_bounds__(256) void wtrans(const float* __restrict__ wq,
                                              const float* __restrict__ wk,
                                              const float* __restrict__ wv,
                                              short* __restrict__ wt) {
    int w = blockIdx.z;
    const float* W = (w == 0) ? wq : (w == 1) ? wk : wv;
    short* O = wt + (size_t)w * 1048576;
    int n0 = blockIdx.x * 64, k0 = blockIdx.y * 64;
    __shared__ float tile[64][65];
    int t = threadIdx.x;
#pragma unroll
    for (int i = 0; i < 16; ++i) {
        int idx = t + i * 256;
        int r = idx >> 6, c = idx & 63;
        tile[r][c] = W[(size_t)(k0 + r) * 1024 + n0 + c];
    }
    __syncthreads();
#pragma unroll
    for (int i = 0; i < 16; ++i) {
        int idx = t + i * 256;
        int r = idx >> 6, c = idx & 63;
        O[(size_t)(n0 + r) * 1024 + k0 + c] = f2bf(tile[c][r]);
    }
}

// ---------------- 256x256 NT GEMM, K-half pipelined ----------------
// C[m][n] = sum_k A[m][k] * B[n][k]
// MODE 0: QK-proj (bf16 out split qb/kb at col 1024), grid (8,32,1)
// MODE 1: merged scores (z<4, causal) + VT (z>=4), grid (8,8,6)
// MODE 2: PV (A=attn bf16 lda=4096; f32 out; Kend=m0+256), grid (4,8,4)
template <int MODE>
__global__ __launch_bounds__(512, 2) void gemm256(
    const short* __restrict__ A0, int lda0, long long sA,
    const short* __restrict__ B0, int ldb0, long long sB,
    void* __restrict__ C0, float scale,
    const short* __restrict__ Av, const short* __restrict__ Bv,
    short* __restrict__ Cv) {

    // T1: XCD-aware bijective block swizzle over the flattened grid
    int bx = blockIdx.x, by = blockIdx.y, bz = blockIdx.z;
    {
        const int gx = gridDim.x, gy = gridDim.y;
        const int nwg = gx * gy * gridDim.z;
        int flat = bx + gx * (by + gy * bz);
        int nf = (flat & 7) * (nwg >> 3) + (flat >> 3);
        bx = nf % gx; int r2 = nf / gx; by = r2 % gy; bz = r2 / gy;
    }

    int m0, n0, lda = lda0, ldb = ldb0;
    const short* Ab;
    const short* Bb;
    bool isVT = false;
    int z = bz;
    if (MODE == 1 && bz >= 4) {
        isVT = true;
        int v = bx + (by << 3) + ((bz - 4) << 6);  // 0..127
        m0 = (v >> 5) << 8;                        // 0..768  (M=1024)
        n0 = (v & 31) << 8;                        // 0..8191 (N=8192)
        Ab = Av; Bb = Bv; lda = 1024; ldb = 1024;
    } else {
        m0 = by * 256;
        n0 = bx * 256;
        if (MODE == 1 && n0 > m0 + 255) return;  // fully above diagonal
        Ab = A0 + (size_t)z * sA;
        Bb = B0 + (size_t)z * sB;
    }

    const int tid = threadIdx.x;
    const int lane = tid & 63;
    const int wid = tid >> 6;
    const int wm = wid >> 2, wn = wid & 3;  // 2x4 waves, wave tile 128x64

    // [buf][khalf][256 rows x 32 shorts] each matrix: 16 KB x 2 x 2 x 2 = 128K
    __shared__ __align__(16) short As[2][2][8192];
    __shared__ __align__(16) short Bs[2][2][8192];

    f32x4 acc[8][4] = {};

    const int Kend = (MODE == 2) ? (m0 + 256) : 1024;
    const int nt = Kend >> 6;  // >= 4

    // staging: 4 thr/row x 16B; 2 loads per (matrix, khalf): rows 0-127,128-255
    const int srow4 = tid >> 2;                       // 0..127
    const int sl4 = (tid & 3) ^ ((tid >> 3) & 3);     // pre-swizzled source slot
    const short* Agp = Ab + (size_t)(m0 + srow4) * lda + sl4 * 8;
    const short* Bgp = Bb + (size_t)(n0 + srow4) * ldb + sl4 * 8;

#define SA(kt, bf, kh)                                                        \
    do {                                                                      \
        const int _k = ((kt) << 6) + ((kh) << 5);                             \
        GLOAD_LDS16(Agp + _k, &As[bf][kh][tid * 8]);                          \
        GLOAD_LDS16(Agp + _k + (size_t)128 * lda, &As[bf][kh][4096 + tid * 8]);\
    } while (0)
#define SB(kt, bf, kh)                                                        \
    do {                                                                      \
        const int _k = ((kt) << 6) + ((kh) << 5);                             \
        GLOAD_LDS16(Bgp + _k, &Bs[bf][kh][tid * 8]);                          \
        GLOAD_LDS16(Bgp + _k + (size_t)128 * ldb, &Bs[bf][kh][4096 + tid * 8]);\
    } while (0)

    const int r = lane & 15;
    const int g = lane >> 4;

#define LDA4(dst, bf, kh, mh)                                                 \
    _Pragma("unroll") for (int q = 0; q < 4; ++q) {                           \
        const int rr = wm * 128 + (mh)*64 + q * 16 + r;                       \
        const int ph = g ^ ((rr >> 1) & 3);                                   \
        dst[q] = *(const bf16x8*)&As[bf][kh][rr * 32 + ph * 8];               \
    }
#define LDB4(dst, bf, kh)                                                     \
    _Pragma("unroll") for (int q = 0; q < 4; ++q) {                           \
        const int rb = wn * 64 + q * 16 + r;                                  \
        const int ph = g ^ ((rb >> 1) & 3);                                   \
        dst[q] = *(const bf16x8*)&Bs[bf][kh][rb * 32 + ph * 8];               \
    }
#define LGKM0()                                                               \
    asm volatile("s_waitcnt lgkmcnt(0)" ::: "memory");                        \
    __builtin_amdgcn_sched_barrier(0)
#define VMC4() asm volatile("s_waitcnt vmcnt(4)" ::: "memory")
#define VMC0() asm volatile("s_waitcnt vmcnt(0)" ::: "memory")
#define BAR() __builtin_amdgcn_s_barrier()
#define MF16(mh, ar, br)                                                      \
    do {                                                                      \
        __builtin_amdgcn_s_setprio(1);                                        \
        _Pragma("unroll") for (int q = 0; q < 4; ++q)                         \
            _Pragma("unroll") for (int ni = 0; ni < 4; ++ni)                  \
                acc[(mh)*4 + q][ni] = __builtin_amdgcn_mfma_f32_16x16x32_bf16(\
                    ar[q], br[ni], acc[(mh)*4 + q][ni], 0, 0, 0);             \
        __builtin_amdgcn_s_setprio(0);                                        \
    } while (0)

    // prologue: stage tile 0 in consumption order; k0 ready, k1 in flight
    SA(0, 0, 0); SB(0, 0, 0); SA(0, 0, 1); SB(0, 0, 1);
    VMC4();
    BAR();

    int buf = 0;
    for (int t = 0; t < nt - 1; ++t) {
        const int nb = buf ^ 1;
        bf16x8 a[4], b[4];
        // p0 (k0, mh0): stage A-k0(t+1)
        SA(t + 1, nb, 0);
        LDA4(a, buf, 0, 0); LDB4(b, buf, 0);
        LGKM0();
        MF16(0, a, b);
        // p1 (k0, mh1): stage B-k0(t+1)
        SB(t + 1, nb, 0);
        LDA4(a, buf, 0, 1);
        LGKM0();
        MF16(1, a, b);
        VMC4();  // k1(t) landed (issued last tile); leaves p0,p1's 4 in flight
        BAR();   // publish k1(t) across waves
        // p2 (k1, mh0): stage A-k1(t+1)
        SA(t + 1, nb, 1);
        LDA4(a, buf, 1, 0); LDB4(b, buf, 1);
        LGKM0();
        MF16(0, a, b);
        // p3 (k1, mh1): stage B-k1(t+1)
        SB(t + 1, nb, 1);
        LDA4(a, buf, 1, 1);
        LGKM0();
        MF16(1, a, b);
        VMC4();  // k0(t+1) landed (issued 3 phases ago); k1(t+1) in flight
        BAR();   // publish + all reads of buf retired -> next stages safe
        buf = nb;
    }
    // peeled last tile: no staging
    {
        bf16x8 a[4], b[4];
        LDA4(a, buf, 0, 0); LDB4(b, buf, 0);
        LGKM0();
        MF16(0, a, b);
        LDA4(a, buf, 0, 1);
        LGKM0();
        MF16(1, a, b);
        VMC0();  // k1(last): the only 4 outstanding
        BAR();
        LDA4(a, buf, 1, 0); LDB4(b, buf, 1);
        LGKM0();
        MF16(0, a, b);
        LDA4(a, buf, 1, 1);
        LGKM0();
        MF16(1, a, b);
    }

    // ---- C epilogue: C/D layout col=lane&15, row=(lane>>4)*4+reg
    const int r4 = (lane >> 4) * 4;
#pragma unroll
    for (int mi = 0; mi < 8; ++mi) {
#pragma unroll
        for (int ni = 0; ni < 4; ++ni) {
            int col = n0 + wn * 64 + ni * 16 + r;
#pragma unroll
            for (int i = 0; i < 4; ++i) {
                int rr = m0 + wm * 128 + mi * 16 + r4 + i;
                float v = acc[mi][ni][i];
                if (MODE == 0) {
                    ((short*)C0)[(size_t)(col >> 10) * 8388608 +
                                 (size_t)rr * 1024 + (col & 1023)] = f2bf(v);
                } else if (MODE == 1) {
                    if (isVT) {
                        Cv[(size_t)(col >> 11) * 2097152 +
                           (size_t)rr * 2048 + (col & 2047)] = f2bf(v);
                    } else if (col <= rr) {
                        ((float*)C0)[(size_t)z * 4194304 +
                                     (size_t)rr * 2048 + col] = v * scale;
                    }
                } else {
                    ((float*)C0)[(size_t)z * 2097152 +
                                 (size_t)rr * 1024 + col] = v;
                }
            }
        }
    }
#undef SA
#undef SB
#undef LDA4
#undef LDB4
#undef LGKM0
#undef VMC4
#undef VMC0
#undef BAR
#undef MF16
}

// ---------------- causal row softmax, f32 scores -> bf16 attn in-place ------
__global__ __launch_bounds__(256) void softmax_causal(float* __restrict__ scores) {
    int row = blockIdx.x;            // 0..8191
    int b = row >> 11, i = row & 2047;
    float* srow = scores + ((size_t)b * 2048 + i) * 2048;
    short* arow = (short*)srow;      // bf16 written over the same row
    __shared__ float sv[2048];
    __shared__ float red[8];
    int t = threadIdx.x;
    int L = i + 1;

    float mx = -1e30f;
    for (int j = t; j < L; j += 256) {
        float v = srow[j];
        sv[j] = v;
        mx = fmaxf(mx, v);
    }
#pragma unroll
    for (int o = 32; o > 0; o >>= 1) mx = fmaxf(mx, __shfl_down(mx, o));
    if ((t & 63) == 0) red[t >> 6] = mx;
    __syncthreads();
    mx = fmaxf(fmaxf(red[0], red[1]), fmaxf(red[2], red[3]));

    float sum = 0.f;
    for (int j = t; j < L; j += 256) {
        float e = __expf(sv[j] - mx);
        sv[j] = e;
        sum += e;
    }
#pragma unroll
    for (int o = 32; o > 0; o >>= 1) sum += __shfl_down(sum, o);
    if ((t & 63) == 0) red[4 + (t >> 6)] = sum;
    __syncthreads();
    sum = red[4] + red[5] + red[6] + red[7];
    float rinv = 1.0f / sum;

    int Lpad = (i | 255) + 1;  // zero-fill to the 256-block edge for PV
    for (int j = t; j < Lpad; j += 256) {
        float p = (j < L) ? sv[j] * rinv : 0.0f;
        arow[j] = f2bf(p);
    }
}

extern "C" void kernel_launch(void* const* d_in, const int* in_sizes, int n_in,
                              void* d_out, int out_size, void* d_ws, size_t ws_size,
                              hipStream_t stream) {
    const float* x  = (const float*)d_in[0];
    const float* wq = (const float*)d_in[1];
    const float* wk = (const float*)d_in[2];
    const float* wv = (const float*)d_in[3];
    float* out = (float*)d_out;

    // workspace layout (shorts)
    short* ws16 = (short*)d_ws;
    short* xb = ws16;                    //  8,388,608 shorts
    short* wt = xb + 8388608;            //  3,145,728  [3][1024][1024]
    short* qb = wt + 3145728;            //  8,388,608  (kb must follow qb!)
    short* kb = qb + 8388608;            //  8,388,608
    short* vt = kb + 8388608;            //  8,388,608  [4][1024][2048]
    float* scores = (float*)(vt + 8388608);  // 4*2048*2048 f32

    convx<<<8192, 256, 0, stream>>>(x, xb, 2097152);
    wtrans<<<dim3(16, 16, 3), 256, 0, stream>>>(wq, wk, wv, wt);
    // Q,K fused: [8192 x 2048] = xb @ [wq^T;wk^T]^T
    gemm256<0><<<dim3(8, 32, 1), 512, 0, stream>>>(
        xb, 1024, 0LL, wt, 1024, 0LL, qb, 1.0f, nullptr, nullptr, nullptr);
    // merged: scores (z<4) + V^T (z=4,5)
    gemm256<1><<<dim3(8, 8, 6), 512, 0, stream>>>(
        qb, 1024, 2097152LL, kb, 1024, 2097152LL, scores, 0.03125f,
        wt + 2097152, xb, vt);
    softmax_causal<<<8192, 256, 0, stream>>>(scores);
    // out = attn @ vt^T, Kend = m0+256
    gemm256<2><<<dim3(4, 8, 4), 512, 0, stream>>>(
        (const short*)scores, 4096, 8388608LL, vt, 2048, 2097152LL, out, 1.0f,
        nullptr, nullptr, nullptr);
}

// Round 7
// 231.238 us; speedup vs baseline: 1.0465x; 1.0166x over previous
//
#include <hip/hip_runtime.h>
#include <hip/hip_bf16.h>

// B=4, S=2048, D=1024. x:[4,2048,1024] f32; wq/wk/wv:[1024,1024] f32.
// out:[4,2048,1024] f32.
//
// Pipeline (bf16 MFMA, fp32 accum):
//   1. convx:  x f32 -> xb bf16                        [8192,1024]
//   2. wtrans: wq/wk/wv f32 -> wt bf16 TRANSPOSED      [3][1024(n)][1024(k)]
//   3. gemm256<0>: qb,kb = xb @ wt[0:2]^T (N=2048 fused), bf16 out
//   4. gemm256<1>: MERGED: z<4 -> scores=(q@k^T)/32 causal; z=4,5 -> vt
//   5. softmax: causal row softmax, bf16 attn in-place, zero-pad to 256-edge
//   6. gemm256<2>: out = attn @ vt^T (Kend = m0+256), f32 out
//
// R7 = R4 phase body (best measured: per-phase {ds_read; BAR; lgkm0+
// sched_barrier; 16 MFMA; BAR}) + ONE change: burst staging. All 8 of
// tile t+1's global_load_lds issue at p0 of tile t (issue-to-wait distance
// 3-4 phases ~1200+ cy vs R4's 1 phase), single vmcnt(0)+BAR at p3-end —
// at that point the only outstanding vmem ops are tile t+1's 8 loads, so
// vmcnt(0) is a counted wait on loads issued ~4 phases earlier.
// LDS layout/swizzle: R4's exactly (measured 0 bank conflicts).

typedef __attribute__((ext_vector_type(8))) short bf16x8;
typedef __attribute__((ext_vector_type(4))) float f32x4;

#define GLOAD_LDS16(g, l)                                                     \
    __builtin_amdgcn_global_load_lds(                                         \
        (const __attribute__((address_space(1))) void*)(g),                   \
        (__attribute__((address_space(3))) void*)(l), 16, 0, 0)

__device__ __forceinline__ short f2bf(float f) {
    union { float f; unsigned u; } v; v.f = f;
    unsigned r = v.u + 0x7FFFu + ((v.u >> 16) & 1u);
    return (short)(r >> 16);
}

// ---------------- convert x to bf16 ----------------
__global__ __launch_bounds__(256) void convx(const float* __restrict__ x,
                                             short* __restrict__ xb, int n4) {
    int i = blockIdx.x * 256 + threadIdx.x;
    if (i < n4) {
        float4 v = ((const float4*)x)[i];
        short4 o;
        o.x = f2bf(v.x); o.y = f2bf(v.y); o.z = f2bf(v.z); o.w = f2bf(v.w);
        ((short4*)xb)[i] = o;
    }
}

// ---------------- weights: f32 [k][n] -> bf16 [n][k] ----------------
__global__ __launch_bounds__(256) void wtrans(const float* __restrict__ wq,
                                              const float* __restrict__ wk,
                                              const float* __restrict__ wv,
                                              short* __restrict__ wt) {
    int w = blockIdx.z;
    const float* W = (w == 0) ? wq : (w == 1) ? wk : wv;
    short* O = wt + (size_t)w * 1048576;
    int n0 = blockIdx.x * 64, k0 = blockIdx.y * 64;
    __shared__ float tile[64][65];
    int t = threadIdx.x;
#pragma unroll
    for (int i = 0; i < 16; ++i) {
        int idx = t + i * 256;
        int r = idx >> 6, c = idx & 63;
        tile[r][c] = W[(size_t)(k0 + r) * 1024 + n0 + c];
    }
    __syncthreads();
#pragma unroll
    for (int i = 0; i < 16; ++i) {
        int idx = t + i * 256;
        int r = idx >> 6, c = idx & 63;
        O[(size_t)(n0 + r) * 1024 + k0 + c] = f2bf(tile[c][r]);
    }
}

// ---------------- 256x256 NT GEMM, R4 body + burst staging ----------------
// C[m][n] = sum_k A[m][k] * B[n][k]
// MODE 0: QK-proj (bf16 out split qb/kb at col 1024), grid (8,32,1)
// MODE 1: merged scores (z<4, causal) + VT (z>=4), grid (8,8,6)
// MODE 2: PV (A=attn bf16 lda=4096; f32 out; Kend=m0+256), grid (4,8,4)
template <int MODE>
__global__ __launch_bounds__(512, 2) void gemm256(
    const short* __restrict__ A0, int lda0, long long sA,
    const short* __restrict__ B0, int ldb0, long long sB,
    void* __restrict__ C0, float scale,
    const short* __restrict__ Av, const short* __restrict__ Bv,
    short* __restrict__ Cv) {

    // T1: XCD-aware bijective block swizzle (all grids are multiples of 8)
    int bx = blockIdx.x, by = blockIdx.y, bz = blockIdx.z;
    {
        const int gx = gridDim.x, gy = gridDim.y;
        const int nwg = gx * gy * gridDim.z;
        int flat = bx + gx * (by + gy * bz);
        int nf = (flat & 7) * (nwg >> 3) + (flat >> 3);
        bx = nf % gx; int r2 = nf / gx; by = r2 % gy; bz = r2 / gy;
    }

    int m0, n0, lda = lda0, ldb = ldb0;
    const short* Ab;
    const short* Bb;
    bool isVT = false;
    int z = bz;
    if (MODE == 1 && bz >= 4) {
        isVT = true;
        int v = bx + (by << 3) + ((bz - 4) << 6);  // 0..127
        m0 = (v >> 5) << 8;                        // 0..768  (M=1024)
        n0 = (v & 31) << 8;                        // 0..8191 (N=8192)
        Ab = Av; Bb = Bv; lda = 1024; ldb = 1024;
    } else {
        m0 = by * 256;
        n0 = bx * 256;
        if (MODE == 1 && n0 > m0 + 255) return;  // fully above diagonal
        Ab = A0 + (size_t)z * sA;
        Bb = B0 + (size_t)z * sB;
    }

    const int tid = threadIdx.x;
    const int lane = tid & 63;
    const int wid = tid >> 6;
    const int wm = wid >> 2, wn = wid & 3;  // 2x4 waves, wave tile 128x64

    // [buf][half: rows 0-127 / 128-255][128 rows x 64 shorts]; 128 KiB total
    __shared__ __align__(16) short As[2][2][8192];
    __shared__ __align__(16) short Bs[2][2][8192];

    f32x4 acc[8][4] = {};

    const int Kend = (MODE == 2) ? (m0 + 256) : 1024;
    const int nt = Kend >> 6;  // >= 4

    // staging: 8 thr/row x 16B. Physical slot (tid&7) of row r holds logical
    // slot (tid&7)^(r&7): pre-swizzled global src, linear LDS dest.
    const int srow = tid >> 3;                  // 0..63
    const int sl = (tid & 7) ^ (srow & 7);
    const short* Agp = Ab + (size_t)(m0 + srow) * lda + sl * 8;
    const short* Bgp = Bb + (size_t)(n0 + srow) * ldb + sl * 8;

#define SA(kt, bf, h)                                                         \
    do {                                                                      \
        const int _k = (kt) << 6;                                             \
        GLOAD_LDS16(Agp + _k + (size_t)((h)*128 + 0) * lda,                   \
                    &As[bf][h][tid * 8]);                                     \
        GLOAD_LDS16(Agp + _k + (size_t)((h)*128 + 64) * lda,                  \
                    &As[bf][h][4096 + tid * 8]);                              \
    } while (0)
#define SB(kt, bf, h)                                                         \
    do {                                                                      \
        const int _k = (kt) << 6;                                             \
        GLOAD_LDS16(Bgp + _k + (size_t)((h)*128 + 0) * ldb,                   \
                    &Bs[bf][h][tid * 8]);                                     \
        GLOAD_LDS16(Bgp + _k + (size_t)((h)*128 + 64) * ldb,                  \
                    &Bs[bf][h][4096 + tid * 8]);                              \
    } while (0)
#define G8(kt, bf)                                                            \
    do { SA(kt, bf, 0); SA(kt, bf, 1); SB(kt, bf, 0); SB(kt, bf, 1); } while (0)

    const int r = lane & 15;
    const int g = lane >> 4;
    const int pxor = r & 7;

#define LDA4(dst, bf, mh, kk)                                                 \
    _Pragma("unroll") for (int q = 0; q < 4; ++q)                             \
        dst[q] = *(const bf16x8*)&As[bf][wm][((mh)*64 + q * 16 + r) * 64 +    \
                                             (((kk)*4 + g) ^ pxor) * 8];
#define LDB4(dst, bf, kk)                                                     \
    _Pragma("unroll") for (int q = 0; q < 4; ++q)                             \
        dst[q] = *(const bf16x8*)&Bs[bf][wn >> 1][((wn & 1) * 64 + q * 16 +   \
                                                   r) * 64 +                  \
                                                  (((kk)*4 + g) ^ pxor) * 8];
#define LGKM0()                                                               \
    asm volatile("s_waitcnt lgkmcnt(0)" ::: "memory");                        \
    __builtin_amdgcn_sched_barrier(0)
#define VM0() asm volatile("s_waitcnt vmcnt(0)" ::: "memory")
#define BAR() __builtin_amdgcn_s_barrier()
#define MF16(mh, ar, br)                                                      \
    do {                                                                      \
        __builtin_amdgcn_s_setprio(1);                                        \
        _Pragma("unroll") for (int q = 0; q < 4; ++q)                         \
            _Pragma("unroll") for (int ni = 0; ni < 4; ++ni)                  \
                acc[(mh)*4 + q][ni] = __builtin_amdgcn_mfma_f32_16x16x32_bf16(\
                    ar[q], br[ni], acc[(mh)*4 + q][ni], 0, 0, 0);             \
        __builtin_amdgcn_s_setprio(0);                                        \
    } while (0)

    // prologue: stage tile 0 (one-time full drain)
    G8(0, 0);
    VM0();
    BAR();

    int buf = 0;
    for (int t = 0; t < nt - 1; ++t) {
        const int nb = buf ^ 1;
        bf16x8 a[4], b[4];
        G8(t + 1, nb);  // burst: 8 loads, 3-4 phases of latency cover
        // p0 (mh0, kk0)
        LDA4(a, buf, 0, 0); LDB4(b, buf, 0);
        BAR();
        LGKM0();
        MF16(0, a, b);
        BAR();
        // p1 (mh1, kk0)
        LDA4(a, buf, 1, 0);
        BAR();
        LGKM0();
        MF16(1, a, b);
        BAR();
        // p2 (mh0, kk1)
        LDA4(a, buf, 0, 1); LDB4(b, buf, 1);
        BAR();
        LGKM0();
        MF16(0, a, b);
        BAR();
        // p3 (mh1, kk1)
        LDA4(a, buf, 1, 1);
        BAR();
        LGKM0();
        MF16(1, a, b);
        VM0();   // only outstanding vmem = tile t+1's 8 loads, issued @p0
        BAR();   // publish tile t+1; all reads of buf retired
        buf = nb;
    }
    // peeled last tile: no staging
    {
        bf16x8 a[4], b[4];
        LDA4(a, buf, 0, 0); LDB4(b, buf, 0);
        BAR();
        LGKM0();
        MF16(0, a, b);
        BAR();
        LDA4(a, buf, 1, 0);
        BAR();
        LGKM0();
        MF16(1, a, b);
        BAR();
        LDA4(a, buf, 0, 1); LDB4(b, buf, 1);
        BAR();
        LGKM0();
        MF16(0, a, b);
        BAR();
        LDA4(a, buf, 1, 1);
        LGKM0();
        MF16(1, a, b);
    }

    // ---- C epilogue: C/D layout col=lane&15, row=(lane>>4)*4+reg
    const int r4 = (lane >> 4) * 4;
#pragma unroll
    for (int mi = 0; mi < 8; ++mi) {
#pragma unroll
        for (int ni = 0; ni < 4; ++ni) {
            int col = n0 + wn * 64 + ni * 16 + r;
#pragma unroll
            for (int i = 0; i < 4; ++i) {
                int rr = m0 + wm * 128 + mi * 16 + r4 + i;
                float v = acc[mi][ni][i];
                if (MODE == 0) {
                    ((short*)C0)[(size_t)(col >> 10) * 8388608 +
                                 (size_t)rr * 1024 + (col & 1023)] = f2bf(v);
                } else if (MODE == 1) {
                    if (isVT) {
                        Cv[(size_t)(col >> 11) * 2097152 +
                           (size_t)rr * 2048 + (col & 2047)] = f2bf(v);
                    } else if (col <= rr) {
                        ((float*)C0)[(size_t)z * 4194304 +
                                     (size_t)rr * 2048 + col] = v * scale;
                    }
                } else {
                    ((float*)C0)[(size_t)z * 2097152 +
                                 (size_t)rr * 1024 + col] = v;
                }
            }
        }
    }
#undef SA
#undef SB
#undef G8
#undef LDA4
#undef LDB4
#undef LGKM0
#undef VM0
#undef BAR
#undef MF16
}

// ---------------- causal row softmax, f32 scores -> bf16 attn in-place ------
__global__ __launch_bounds__(256) void softmax_causal(float* __restrict__ scores) {
    int row = blockIdx.x;            // 0..8191
    int b = row >> 11, i = row & 2047;
    float* srow = scores + ((size_t)b * 2048 + i) * 2048;
    short* arow = (short*)srow;      // bf16 written over the same row
    __shared__ float sv[2048];
    __shared__ float red[8];
    int t = threadIdx.x;
    int L = i + 1;

    float mx = -1e30f;
    for (int j = t; j < L; j += 256) {
        float v = srow[j];
        sv[j] = v;
        mx = fmaxf(mx, v);
    }
#pragma unroll
    for (int o = 32; o > 0; o >>= 1) mx = fmaxf(mx, __shfl_down(mx, o));
    if ((t & 63) == 0) red[t >> 6] = mx;
    __syncthreads();
    mx = fmaxf(fmaxf(red[0], red[1]), fmaxf(red[2], red[3]));

    float sum = 0.f;
    for (int j = t; j < L; j += 256) {
        float e = __expf(sv[j] - mx);
        sv[j] = e;
        sum += e;
    }
#pragma unroll
    for (int o = 32; o > 0; o >>= 1) sum += __shfl_down(sum, o);
    if ((t & 63) == 0) red[4 + (t >> 6)] = sum;
    __syncthreads();
    sum = red[4] + red[5] + red[6] + red[7];
    float rinv = 1.0f / sum;

    int Lpad = (i | 255) + 1;  // zero-fill to the 256-block edge for PV
    for (int j = t; j < Lpad; j += 256) {
        float p = (j < L) ? sv[j] * rinv : 0.0f;
        arow[j] = f2bf(p);
    }
}

extern "C" void kernel_launch(void* const* d_in, const int* in_sizes, int n_in,
                              void* d_out, int out_size, void* d_ws, size_t ws_size,
                              hipStream_t stream) {
    const float* x  = (const float*)d_in[0];
    const float* wq = (const float*)d_in[1];
    const float* wk = (const float*)d_in[2];
    const float* wv = (const float*)d_in[3];
    float* out = (float*)d_out;

    // workspace layout (shorts)
    short* ws16 = (short*)d_ws;
    short* xb = ws16;                    //  8,388,608 shorts
    short* wt = xb + 8388608;            //  3,145,728  [3][1024][1024]
    short* qb = wt + 3145728;            //  8,388,608  (kb must follow qb!)
    short* kb = qb + 8388608;            //  8,388,608
    short* vt = kb + 8388608;            //  8,388,608  [4][1024][2048]
    float* scores = (float*)(vt + 8388608);  // 4*2048*2048 f32

    convx<<<8192, 256, 0, stream>>>(x, xb, 2097152);
    wtrans<<<dim3(16, 16, 3), 256, 0, stream>>>(wq, wk, wv, wt);
    // Q,K fused: [8192 x 2048] = xb @ [wq^T;wk^T]^T
    gemm256<0><<<dim3(8, 32, 1), 512, 0, stream>>>(
        xb, 1024, 0LL, wt, 1024, 0LL, qb, 1.0f, nullptr, nullptr, nullptr);
    // merged: scores (z<4) + V^T (z=4,5)
    gemm256<1><<<dim3(8, 8, 6), 512, 0, stream>>>(
        qb, 1024, 2097152LL, kb, 1024, 2097152LL, scores, 0.03125f,
        wt + 2097152, xb, vt);
    softmax_causal<<<8192, 256, 0, stream>>>(scores);
    // out = attn @ vt^T, Kend = m0+256
    gemm256<2><<<dim3(4, 8, 4), 512, 0, stream>>>(
        (const short*)scores, 4096, 8388608LL, vt, 2048, 2097152LL, out, 1.0f,
        nullptr, nullptr, nullptr);
}

// Round 8
// 172.416 us; speedup vs baseline: 1.4035x; 1.3412x over previous
//
#include <hip/hip_runtime.h>
#include <hip/hip_bf16.h>

// B=4, S=2048, D=1024. x:[4,2048,1024] f32; wq/wk/wv:[1024,1024] f32.
// out:[4,2048,1024] f32.
//
// Pipeline (bf16 MFMA, fp32 accum):
//   1. convx:  x f32 -> xb bf16                        [8192,1024]
//   2. wtrans: wq/wk/wv f32 -> wt bf16 TRANSPOSED      [3][1024(n)][1024(k)]
//   3. gemm128<0>: qb,kb = xb @ [wq^T;wk^T]^T, 1024 uniform blocks
//   4. gemm128<1>: MERGED 1056 blocks: bid<544 -> live-triangular scores
//                  blocks (no dead blocks); bid>=544 -> vt = wv^T @ xb^T
//   5. softmax: causal row softmax, bf16 attn in-place, zero-pad
//   6. gemm128<2>: out = attn @ vt^T, 512 blocks (Kend = m0+128)
//
// R8: consolidate on the catalog-proven config: 128^2 tile, BK=64, 4 waves
// (2x2, wave tile 64x64), 64 KiB LDS double-buffer -> 2 blocks/CU
// (m114 inter-block overlap), minimum 2-phase loop (T3 recipe): per K-tile
// {STAGE(t+1); ds_read+lgkm0+MFMA x2; vmcnt(0); ONE barrier} — vs R4's
// 8 barriers/tile at 1 block/CU. No setprio (m190: negative on 2ph).
// Swizzle: R4's measured-0-conflict scheme (phys slot = logical ^ (row&7),
// both-sides: pre-swizzled global source + swizzled ds_read).
// Fill/balance: only live causal blocks enumerated; VT merged into the
// scores dispatch; all grids multiple of 8 for the XCD swizzle.

typedef __attribute__((ext_vector_type(8))) short bf16x8;
typedef __attribute__((ext_vector_type(4))) float f32x4;

#define GLOAD_LDS16(g, l)                                                     \
    __builtin_amdgcn_global_load_lds(                                         \
        (const __attribute__((address_space(1))) void*)(g),                   \
        (__attribute__((address_space(3))) void*)(l), 16, 0, 0)

__device__ __forceinline__ short f2bf(float f) {
    union { float f; unsigned u; } v; v.f = f;
    unsigned r = v.u + 0x7FFFu + ((v.u >> 16) & 1u);
    return (short)(r >> 16);
}

// ---------------- convert x to bf16 ----------------
__global__ __launch_bounds__(256) void convx(const float* __restrict__ x,
                                             short* __restrict__ xb, int n4) {
    int i = blockIdx.x * 256 + threadIdx.x;
    if (i < n4) {
        float4 v = ((const float4*)x)[i];
        short4 o;
        o.x = f2bf(v.x); o.y = f2bf(v.y); o.z = f2bf(v.z); o.w = f2bf(v.w);
        ((short4*)xb)[i] = o;
    }
}

// ---------------- weights: f32 [k][n] -> bf16 [n][k] ----------------
__global__ __launch_bounds__(256) void wtrans(const float* __restrict__ wq,
                                              const float* __restrict__ wk,
                                              const float* __restrict__ wv,
                                              short* __restrict__ wt) {
    int w = blockIdx.z;
    const float* W = (w == 0) ? wq : (w == 1) ? wk : wv;
    short* O = wt + (size_t)w * 1048576;
    int n0 = blockIdx.x * 64, k0 = blockIdx.y * 64;
    __shared__ float tile[64][65];
    int t = threadIdx.x;
#pragma unroll
    for (int i = 0; i < 16; ++i) {
        int idx = t + i * 256;
        int r = idx >> 6, c = idx & 63;
        tile[r][c] = W[(size_t)(k0 + r) * 1024 + n0 + c];
    }
    __syncthreads();
#pragma unroll
    for (int i = 0; i < 16; ++i) {
        int idx = t + i * 256;
        int r = idx >> 6, c = idx & 63;
        O[(size_t)(n0 + r) * 1024 + k0 + c] = f2bf(tile[c][r]);
    }
}

// ---------------- 128x128 NT GEMM, 2-phase, 2 blocks/CU ----------------
// C[m][n] = sum_k A[m][k] * B[n][k]
// MODE 0: QK-proj, grid 1024 (mt=bid>>4, nt=bid&15); bf16 out qb/kb split
// MODE 1: merged, grid 1056: bid<544 scores (triangular decode, causal
//         predicate, f32 *scale); bid>=544 VT (bf16 out [4][1024][2048])
// MODE 2: PV, grid 512 (z=bid>>7, mt=(bid&127)>>3, nt=bid&7); Kend=m0+128
template <int MODE>
__global__ __launch_bounds__(256, 2) void gemm128(
    const short* __restrict__ A0, int lda0, long long sA,
    const short* __restrict__ B0, int ldb0, long long sB,
    void* __restrict__ C0, float scale,
    const short* __restrict__ Av, const short* __restrict__ Bv,
    short* __restrict__ Cv) {

    // T1: XCD swizzle (grid.x always a multiple of 8)
    int bid;
    {
        const int nblk = gridDim.x;
        const int raw = blockIdx.x;
        bid = (raw & 7) * (nblk >> 3) + (raw >> 3);
    }

    int m0, n0, z = 0, lda = lda0, ldb = ldb0;
    const short* Ab;
    const short* Bb;
    bool isVT = false;

    if (MODE == 0) {
        m0 = (bid >> 4) * 128;        // M=8192
        n0 = (bid & 15) * 128;        // N=2048
        Ab = A0; Bb = B0;
    } else if (MODE == 1) {
        if (bid < 544) {
            z = bid >> 7;  // not valid (136/z) — compute via div below
            z = bid / 136;
            int f = bid - z * 136;
            int mt = (int)((sqrtf(8.f * f + 1.f) - 1.f) * 0.5f);
            if (mt * (mt + 1) / 2 > f) --mt;
            if ((mt + 1) * (mt + 2) / 2 <= f) ++mt;
            int nt_ = f - mt * (mt + 1) / 2;   // nt_ <= mt (causal live)
            m0 = mt * 128; n0 = nt_ * 128;
            Ab = A0 + (size_t)z * sA;
            Bb = B0 + (size_t)z * sB;
        } else {
            isVT = true;
            int v = bid - 544;            // 0..511
            m0 = (v >> 6) * 128;          // M=1024
            n0 = (v & 63) * 128;          // N=8192
            Ab = Av; Bb = Bv; lda = 1024; ldb = 1024;
        }
    } else {
        z = bid >> 7;
        int rem = bid & 127;
        m0 = (rem >> 3) * 128;        // M=2048
        n0 = (rem & 7) * 128;         // N=1024
        Ab = A0 + (size_t)z * sA;
        Bb = B0 + (size_t)z * sB;
    }

    const int tid = threadIdx.x;
    const int lane = tid & 63;
    const int wid = tid >> 6;
    const int wm = wid >> 1, wn = wid & 1;  // 2x2 waves, wave tile 64x64

    // [buf][128 rows x 64 shorts] per matrix: 16 KB x2 bufs x2 mats = 64 KiB
    __shared__ __align__(16) short As[2][8192];
    __shared__ __align__(16) short Bs[2][8192];

    f32x4 acc[4][4] = {};

    const int Kend = (MODE == 2) ? (m0 + 128) : 1024;
    const int nt = Kend >> 6;  // MODE0/1: 16; MODE2: 2..32

    // staging: 8 thr/row x 16B, 4 row-passes (+32 rows each).
    // Physical slot (tid&7) of row r holds logical slot (tid&7)^(r&7):
    // pre-swizzled global source, linear LDS dest ((r&7) invariant under +32).
    const int srow = tid >> 3;                  // 0..31
    const int sl = (tid & 7) ^ (srow & 7);
    const short* Agp = Ab + (size_t)(m0 + srow) * lda + sl * 8;
    const short* Bgp = Bb + (size_t)(n0 + srow) * ldb + sl * 8;

#define SA(kt, bf)                                                            \
    do {                                                                      \
        const int _k = (kt) << 6;                                             \
        GLOAD_LDS16(Agp + _k,                     &As[bf][tid * 8]);          \
        GLOAD_LDS16(Agp + _k + (size_t)32 * lda,  &As[bf][2048 + tid * 8]);   \
        GLOAD_LDS16(Agp + _k + (size_t)64 * lda,  &As[bf][4096 + tid * 8]);   \
        GLOAD_LDS16(Agp + _k + (size_t)96 * lda,  &As[bf][6144 + tid * 8]);   \
    } while (0)
#define SB(kt, bf)                                                            \
    do {                                                                      \
        const int _k = (kt) << 6;                                             \
        GLOAD_LDS16(Bgp + _k,                     &Bs[bf][tid * 8]);          \
        GLOAD_LDS16(Bgp + _k + (size_t)32 * ldb,  &Bs[bf][2048 + tid * 8]);   \
        GLOAD_LDS16(Bgp + _k + (size_t)64 * ldb,  &Bs[bf][4096 + tid * 8]);   \
        GLOAD_LDS16(Bgp + _k + (size_t)96 * ldb,  &Bs[bf][6144 + tid * 8]);   \
    } while (0)

    const int r = lane & 15;
    const int g = lane >> 4;

#define LDA4(dst, bf, kk)                                                     \
    _Pragma("unroll") for (int q = 0; q < 4; ++q) {                           \
        const int rr = wm * 64 + q * 16 + r;                                  \
        dst[q] = *(const bf16x8*)&As[bf][rr * 64 +                            \
                                         ((((kk)*4 + g) ^ (rr & 7))) * 8];    \
    }
#define LDB4(dst, bf, kk)                                                     \
    _Pragma("unroll") for (int q = 0; q < 4; ++q) {                           \
        const int rb = wn * 64 + q * 16 + r;                                  \
        dst[q] = *(const bf16x8*)&Bs[bf][rb * 64 +                            \
                                         ((((kk)*4 + g) ^ (rb & 7))) * 8];    \
    }
#define LGKM0()                                                               \
    asm volatile("s_waitcnt lgkmcnt(0)" ::: "memory");                        \
    __builtin_amdgcn_sched_barrier(0)
#define VM0() asm volatile("s_waitcnt vmcnt(0)" ::: "memory")
#define BAR() __builtin_amdgcn_s_barrier()
#define MF(ar, br)                                                            \
    _Pragma("unroll") for (int mi = 0; mi < 4; ++mi)                          \
        _Pragma("unroll") for (int ni = 0; ni < 4; ++ni)                      \
            acc[mi][ni] = __builtin_amdgcn_mfma_f32_16x16x32_bf16(            \
                ar[mi], br[ni], acc[mi][ni], 0, 0, 0);

    // prologue: stage tile 0
    SA(0, 0); SB(0, 0);
    VM0();
    BAR();

    int buf = 0;
    for (int t = 0; t < nt - 1; ++t) {
        const int nb = buf ^ 1;
        SA(t + 1, nb); SB(t + 1, nb);   // issue BEFORE compute (T3 recipe)
        bf16x8 a[4], b[4];
        LDA4(a, buf, 0); LDB4(b, buf, 0);
        LGKM0();
        MF(a, b);
        LDA4(a, buf, 1); LDB4(b, buf, 1);
        LGKM0();
        MF(a, b);
        VM0();   // tile t+1 landed (issued one full compute-phase ago)
        BAR();   // publish; all reads of buf retired before next STAGE hits it
        buf = nb;
    }
    // last tile
    {
        bf16x8 a[4], b[4];
        LDA4(a, buf, 0); LDB4(b, buf, 0);
        LGKM0();
        MF(a, b);
        LDA4(a, buf, 1); LDB4(b, buf, 1);
        LGKM0();
        MF(a, b);
    }

    // ---- C epilogue: C/D layout col=lane&15, row=(lane>>4)*4+reg
    const int r4 = (lane >> 4) * 4;
#pragma unroll
    for (int mi = 0; mi < 4; ++mi) {
#pragma unroll
        for (int ni = 0; ni < 4; ++ni) {
            int col = n0 + wn * 64 + ni * 16 + r;
#pragma unroll
            for (int i = 0; i < 4; ++i) {
                int rr = m0 + wm * 64 + mi * 16 + r4 + i;
                float v = acc[mi][ni][i];
                if (MODE == 0) {
                    ((short*)C0)[(size_t)(col >> 10) * 8388608 +
                                 (size_t)rr * 1024 + (col & 1023)] = f2bf(v);
                } else if (MODE == 1) {
                    if (isVT) {
                        Cv[(size_t)(col >> 11) * 2097152 +
                           (size_t)rr * 2048 + (col & 2047)] = f2bf(v);
                    } else if (col <= rr) {
                        ((float*)C0)[(size_t)z * 4194304 +
                                     (size_t)rr * 2048 + col] = v * scale;
                    }
                } else {
                    ((float*)C0)[(size_t)z * 2097152 +
                                 (size_t)rr * 1024 + col] = v;
                }
            }
        }
    }
#undef SA
#undef SB
#undef LDA4
#undef LDB4
#undef LGKM0
#undef VM0
#undef BAR
#undef MF
}

// ---------------- causal row softmax, f32 scores -> bf16 attn in-place ------
__global__ __launch_bounds__(256) void softmax_causal(float* __restrict__ scores) {
    int row = blockIdx.x;            // 0..8191
    int b = row >> 11, i = row & 2047;
    float* srow = scores + ((size_t)b * 2048 + i) * 2048;
    short* arow = (short*)srow;      // bf16 written over the same row
    __shared__ float sv[2048];
    __shared__ float red[8];
    int t = threadIdx.x;
    int L = i + 1;

    float mx = -1e30f;
    for (int j = t; j < L; j += 256) {
        float v = srow[j];
        sv[j] = v;
        mx = fmaxf(mx, v);
    }
#pragma unroll
    for (int o = 32; o > 0; o >>= 1) mx = fmaxf(mx, __shfl_down(mx, o));
    if ((t & 63) == 0) red[t >> 6] = mx;
    __syncthreads();
    mx = fmaxf(fmaxf(red[0], red[1]), fmaxf(red[2], red[3]));

    float sum = 0.f;
    for (int j = t; j < L; j += 256) {
        float e = __expf(sv[j] - mx);
        sv[j] = e;
        sum += e;
    }
#pragma unroll
    for (int o = 32; o > 0; o >>= 1) sum += __shfl_down(sum, o);
    if ((t & 63) == 0) red[4 + (t >> 6)] = sum;
    __syncthreads();
    sum = red[4] + red[5] + red[6] + red[7];
    float rinv = 1.0f / sum;

    int Lpad = (i | 255) + 1;  // zero-fill past the causal edge for PV reads
    for (int j = t; j < Lpad; j += 256) {
        float p = (j < L) ? sv[j] * rinv : 0.0f;
        arow[j] = f2bf(p);
    }
}

extern "C" void kernel_launch(void* const* d_in, const int* in_sizes, int n_in,
                              void* d_out, int out_size, void* d_ws, size_t ws_size,
                              hipStream_t stream) {
    const float* x  = (const float*)d_in[0];
    const float* wq = (const float*)d_in[1];
    const float* wk = (const float*)d_in[2];
    const float* wv = (const float*)d_in[3];
    float* out = (float*)d_out;

    // workspace layout (shorts)
    short* ws16 = (short*)d_ws;
    short* xb = ws16;                    //  8,388,608 shorts
    short* wt = xb + 8388608;            //  3,145,728  [3][1024][1024]
    short* qb = wt + 3145728;            //  8,388,608  (kb must follow qb!)
    short* kb = qb + 8388608;            //  8,388,608
    short* vt = kb + 8388608;            //  8,388,608  [4][1024][2048]
    float* scores = (float*)(vt + 8388608);  // 4*2048*2048 f32

    convx<<<8192, 256, 0, stream>>>(x, xb, 2097152);
    wtrans<<<dim3(16, 16, 3), 256, 0, stream>>>(wq, wk, wv, wt);
    // Q,K fused: [8192 x 2048] = xb @ [wq^T;wk^T]^T  (1024 uniform blocks)
    gemm128<0><<<1024, 256, 0, stream>>>(
        xb, 1024, 0LL, wt, 1024, 0LL, qb, 1.0f, nullptr, nullptr, nullptr);
    // merged: live-triangular scores (544) + V^T (512) = 1056 blocks
    gemm128<1><<<1056, 256, 0, stream>>>(
        qb, 1024, 2097152LL, kb, 1024, 2097152LL, scores, 0.03125f,
        wt + 2097152, xb, vt);
    softmax_causal<<<8192, 256, 0, stream>>>(scores);
    // out = attn @ vt^T, Kend = m0+128  (512 blocks, 2/CU)
    gemm128<2><<<512, 256, 0, stream>>>(
        (const short*)scores, 4096, 8388608LL, vt, 2048, 2097152LL, out, 1.0f,
        nullptr, nullptr, nullptr);
}

// Round 9
// 171.427 us; speedup vs baseline: 1.4116x; 1.0058x over previous
//
#include <hip/hip_runtime.h>
#include <hip/hip_bf16.h>

// B=4, S=2048, D=1024. x:[4,2048,1024] f32; wq/wk/wv:[1024,1024] f32.
// out:[4,2048,1024] f32.
//
// R9 pipeline (bf16 MFMA, fp32 accum). Key algebra: scores = q k^T /32
//   = x (Wq Wk^T / 32) x^T  — precompute the 1024^2 middle matrix, saving
//   the entire K-projection (34.4 GF -> 2.1 + 17.2 GF).
//   1. convx: x->xb bf16; wq->wqb, wk->wkb bf16 (row-major)
//   2. wtrans: wv -> wtv bf16 transposed [1024(n)][1024(k)]
//   3. gemm128<5>: Mt = (wkb @ wqb^T) * (1/32)   [1024x1024] bf16 (= M^T)
//   4. gemm128<5>: t = xb @ Mt^T = x M           [8192x1024] bf16
//   5. gemm128<1>: MERGED: bid<544 live-triangular scores = t @ xb^T (f32),
//                  bid>=544 vt = wtv @ xb^T  [4][1024(d)][2048(s)] bf16
//   6. softmax: causal row softmax (float4/short4 vectorized), bf16 in-place
//   7. gemm128<2>: out = attn @ vt^T, K=m0+128; heavy/light PAIRED block map
//                  (slot i & i+256 carry mt and 15-mt: balanced CU loads)
//
// GEMM structure: R8's proven config — 128^2 tile, BK=64, 4 waves, 64 KiB
// LDS dbuf (2 blocks/CU), 2-phase loop {STAGE(t+1); (ds_read,lgkm0,MFMA)x2;
// vmcnt(0); BAR}, 0-conflict XOR swizzle, XCD swizzle (except PV).

typedef __attribute__((ext_vector_type(8))) short bf16x8;
typedef __attribute__((ext_vector_type(4))) float f32x4;

#define GLOAD_LDS16(g, l)                                                     \
    __builtin_amdgcn_global_load_lds(                                         \
        (const __attribute__((address_space(1))) void*)(g),                   \
        (__attribute__((address_space(3))) void*)(l), 16, 0, 0)

__device__ __forceinline__ short f2bf(float f) {
    union { float f; unsigned u; } v; v.f = f;
    unsigned r = v.u + 0x7FFFu + ((v.u >> 16) & 1u);
    return (short)(r >> 16);
}

// ---------------- convert f32 -> bf16 (x, wq, wk) ----------------
__global__ __launch_bounds__(256) void convx(const float* __restrict__ x,
                                             short* __restrict__ xb, int n4) {
    int i = blockIdx.x * 256 + threadIdx.x;
    if (i < n4) {
        float4 v = ((const float4*)x)[i];
        short4 o;
        o.x = f2bf(v.x); o.y = f2bf(v.y); o.z = f2bf(v.z); o.w = f2bf(v.w);
        ((short4*)xb)[i] = o;
    }
}

// ---------------- wv: f32 [k][n] -> bf16 [n][k] ----------------
__global__ __launch_bounds__(256) void wtrans(const float* __restrict__ W,
                                              short* __restrict__ O) {
    int n0 = blockIdx.x * 64, k0 = blockIdx.y * 64;
    __shared__ float tile[64][65];
    int t = threadIdx.x;
#pragma unroll
    for (int i = 0; i < 16; ++i) {
        int idx = t + i * 256;
        int r = idx >> 6, c = idx & 63;
        tile[r][c] = W[(size_t)(k0 + r) * 1024 + n0 + c];
    }
    __syncthreads();
#pragma unroll
    for (int i = 0; i < 16; ++i) {
        int idx = t + i * 256;
        int r = idx >> 6, c = idx & 63;
        O[(size_t)(n0 + r) * 1024 + k0 + c] = f2bf(tile[c][r]);
    }
}

// ---------------- 128x128 NT GEMM, 2-phase, 2 blocks/CU ----------------
// C[m][n] = sum_k A[m][k] * B[n][k]
// MODE 5: plain bf16 out (ld 1024), *scale; grid = (M/128)*8, N=1024
// MODE 1: merged, grid 1056: bid<544 scores (triangular, causal, f32);
//         bid>=544 VT (bf16 out [4][1024][2048] col-split)
// MODE 2: PV, grid 512, paired heavy/light decode (no XCD swizzle)
template <int MODE>
__global__ __launch_bounds__(256, 2) void gemm128(
    const short* __restrict__ A0, int lda0, long long sA,
    const short* __restrict__ B0, int ldb0, long long sB,
    void* __restrict__ C0, float scale,
    const short* __restrict__ Av, const short* __restrict__ Bv,
    short* __restrict__ Cv) {

    int m0, n0, z = 0, lda = lda0, ldb = ldb0;
    const short* Ab;
    const short* Bb;
    bool isVT = false;

    if (MODE == 2) {
        // paired decode: slots i and i+256 carry mt and 15-mt (sum const),
        // so each CU (2 blocks) gets a balanced K-load. No XCD swizzle.
        int i = blockIdx.x;            // 0..511
        int j = i & 255;
        int mt = (i < 256) ? (15 - (j >> 5)) : (j >> 5);
        z = (j >> 3) & 3;
        m0 = mt * 128;
        n0 = (j & 7) * 128;
        Ab = A0 + (size_t)z * sA;
        Bb = B0 + (size_t)z * sB;
    } else {
        // T1: XCD swizzle (grids are multiples of 8)
        const int nblk = gridDim.x;
        const int raw = blockIdx.x;
        int bid = (raw & 7) * (nblk >> 3) + (raw >> 3);
        if (MODE == 5) {
            m0 = (bid >> 3) * 128;        // M = nblk/8*128
            n0 = (bid & 7) * 128;         // N = 1024
            Ab = A0; Bb = B0;
        } else {  // MODE 1
            if (bid < 544) {
                z = bid / 136;
                int f = bid - z * 136;
                int mt = (int)((sqrtf(8.f * f + 1.f) - 1.f) * 0.5f);
                if (mt * (mt + 1) / 2 > f) --mt;
                if ((mt + 1) * (mt + 2) / 2 <= f) ++mt;
                int nt_ = f - mt * (mt + 1) / 2;   // nt_ <= mt (live)
                m0 = mt * 128; n0 = nt_ * 128;
                Ab = A0 + (size_t)z * sA;
                Bb = B0 + (size_t)z * sB;
            } else {
                isVT = true;
                int v = bid - 544;            // 0..511
                m0 = (v >> 6) * 128;          // M=1024
                n0 = (v & 63) * 128;          // N=8192
                Ab = Av; Bb = Bv; lda = 1024; ldb = 1024;
            }
        }
    }

    const int tid = threadIdx.x;
    const int lane = tid & 63;
    const int wid = tid >> 6;
    const int wm = wid >> 1, wn = wid & 1;  // 2x2 waves, wave tile 64x64

    __shared__ __align__(16) short As[2][8192];
    __shared__ __align__(16) short Bs[2][8192];

    f32x4 acc[4][4] = {};

    const int Kend = (MODE == 2) ? (m0 + 128) : 1024;
    const int nt = Kend >> 6;

    // staging: 8 thr/row x 16B, 4 row-passes. Physical slot (tid&7) of row r
    // holds logical slot (tid&7)^(r&7): pre-swizzled source, linear dest.
    const int srow = tid >> 3;                  // 0..31
    const int sl = (tid & 7) ^ (srow & 7);
    const short* Agp = Ab + (size_t)(m0 + srow) * lda + sl * 8;
    const short* Bgp = Bb + (size_t)(n0 + srow) * ldb + sl * 8;

#define SA(kt, bf)                                                            \
    do {                                                                      \
        const int _k = (kt) << 6;                                             \
        GLOAD_LDS16(Agp + _k,                     &As[bf][tid * 8]);          \
        GLOAD_LDS16(Agp + _k + (size_t)32 * lda,  &As[bf][2048 + tid * 8]);   \
        GLOAD_LDS16(Agp + _k + (size_t)64 * lda,  &As[bf][4096 + tid * 8]);   \
        GLOAD_LDS16(Agp + _k + (size_t)96 * lda,  &As[bf][6144 + tid * 8]);   \
    } while (0)
#define SB(kt, bf)                                                            \
    do {                                                                      \
        const int _k = (kt) << 6;                                             \
        GLOAD_LDS16(Bgp + _k,                     &Bs[bf][tid * 8]);          \
        GLOAD_LDS16(Bgp + _k + (size_t)32 * ldb,  &Bs[bf][2048 + tid * 8]);   \
        GLOAD_LDS16(Bgp + _k + (size_t)64 * ldb,  &Bs[bf][4096 + tid * 8]);   \
        GLOAD_LDS16(Bgp + _k + (size_t)96 * ldb,  &Bs[bf][6144 + tid * 8]);   \
    } while (0)

    const int r = lane & 15;
    const int g = lane >> 4;

#define LDA4(dst, bf, kk)                                                     \
    _Pragma("unroll") for (int q = 0; q < 4; ++q) {                           \
        const int rr = wm * 64 + q * 16 + r;                                  \
        dst[q] = *(const bf16x8*)&As[bf][rr * 64 +                            \
                                         ((((kk)*4 + g) ^ (rr & 7))) * 8];    \
    }
#define LDB4(dst, bf, kk)                                                     \
    _Pragma("unroll") for (int q = 0; q < 4; ++q) {                           \
        const int rb = wn * 64 + q * 16 + r;                                  \
        dst[q] = *(const bf16x8*)&Bs[bf][rb * 64 +                            \
                                         ((((kk)*4 + g) ^ (rb & 7))) * 8];    \
    }
#define LGKM0()                                                               \
    asm volatile("s_waitcnt lgkmcnt(0)" ::: "memory");                        \
    __builtin_amdgcn_sched_barrier(0)
#define VM0() asm volatile("s_waitcnt vmcnt(0)" ::: "memory")
#define BAR() __builtin_amdgcn_s_barrier()
#define MF(ar, br)                                                            \
    _Pragma("unroll") for (int mi = 0; mi < 4; ++mi)                          \
        _Pragma("unroll") for (int ni = 0; ni < 4; ++ni)                      \
            acc[mi][ni] = __builtin_amdgcn_mfma_f32_16x16x32_bf16(            \
                ar[mi], br[ni], acc[mi][ni], 0, 0, 0);

    SA(0, 0); SB(0, 0);
    VM0();
    BAR();

    int buf = 0;
    for (int t = 0; t < nt - 1; ++t) {
        const int nb = buf ^ 1;
        SA(t + 1, nb); SB(t + 1, nb);
        bf16x8 a[4], b[4];
        LDA4(a, buf, 0); LDB4(b, buf, 0);
        LGKM0();
        MF(a, b);
        LDA4(a, buf, 1); LDB4(b, buf, 1);
        LGKM0();
        MF(a, b);
        VM0();
        BAR();
        buf = nb;
    }
    {
        bf16x8 a[4], b[4];
        LDA4(a, buf, 0); LDB4(b, buf, 0);
        LGKM0();
        MF(a, b);
        LDA4(a, buf, 1); LDB4(b, buf, 1);
        LGKM0();
        MF(a, b);
    }

    // ---- C epilogue: C/D layout col=lane&15, row=(lane>>4)*4+reg
    const int r4 = (lane >> 4) * 4;
#pragma unroll
    for (int mi = 0; mi < 4; ++mi) {
#pragma unroll
        for (int ni = 0; ni < 4; ++ni) {
            int col = n0 + wn * 64 + ni * 16 + r;
#pragma unroll
            for (int i = 0; i < 4; ++i) {
                int rr = m0 + wm * 64 + mi * 16 + r4 + i;
                float v = acc[mi][ni][i];
                if (MODE == 5) {
                    ((short*)C0)[(size_t)rr * 1024 + col] = f2bf(v * scale);
                } else if (MODE == 1) {
                    if (isVT) {
                        Cv[(size_t)(col >> 11) * 2097152 +
                           (size_t)rr * 2048 + (col & 2047)] = f2bf(v);
                    } else if (col <= rr) {
                        ((float*)C0)[(size_t)z * 4194304 +
                                     (size_t)rr * 2048 + col] = v;
                    }
                } else {
                    ((float*)C0)[(size_t)z * 2097152 +
                                 (size_t)rr * 1024 + col] = v;
                }
            }
        }
    }
#undef SA
#undef SB
#undef LDA4
#undef LDB4
#undef LGKM0
#undef VM0
#undef BAR
#undef MF
}

// ------- causal row softmax, vectorized: f32 scores -> bf16 in-place -------
__global__ __launch_bounds__(256) void softmax_causal(float* __restrict__ scores) {
    int row = blockIdx.x;            // 0..8191
    int b = row >> 11, i = row & 2047;
    float* srow = scores + ((size_t)b * 2048 + i) * 2048;
    short* arow = (short*)srow;      // bf16 written over the same row
    __shared__ float4 sv4[512];
    __shared__ float red[8];
    int t = threadIdx.x;
    int L = i + 1;
    int nv = (L + 3) >> 2;

    float mx = -1e30f;
    for (int v = t; v < nv; v += 256) {
        float4 w = ((const float4*)srow)[v];
        int base = v << 2;
        w.x = (base + 0 < L) ? w.x : -1e30f;
        w.y = (base + 1 < L) ? w.y : -1e30f;
        w.z = (base + 2 < L) ? w.z : -1e30f;
        w.w = (base + 3 < L) ? w.w : -1e30f;
        sv4[v] = w;
        mx = fmaxf(mx, fmaxf(fmaxf(w.x, w.y), fmaxf(w.z, w.w)));
    }
#pragma unroll
    for (int o = 32; o > 0; o >>= 1) mx = fmaxf(mx, __shfl_down(mx, o));
    if ((t & 63) == 0) red[t >> 6] = mx;
    __syncthreads();
    mx = fmaxf(fmaxf(red[0], red[1]), fmaxf(red[2], red[3]));

    float sum = 0.f;
    for (int v = t; v < nv; v += 256) {
        float4 w = sv4[v];
        float4 e;
        e.x = __expf(w.x - mx);  // masked entries: exp(-1e30-mx) == 0
        e.y = __expf(w.y - mx);
        e.z = __expf(w.z - mx);
        e.w = __expf(w.w - mx);
        sv4[v] = e;
        sum += (e.x + e.y) + (e.z + e.w);
    }
#pragma unroll
    for (int o = 32; o > 0; o >>= 1) sum += __shfl_down(sum, o);
    if ((t & 63) == 0) red[4 + (t >> 6)] = sum;
    __syncthreads();
    sum = red[4] + red[5] + red[6] + red[7];
    float rinv = 1.0f / sum;

    int npad = ((i | 127) + 1) >> 2;  // zero-fill to 128-block edge for PV
    for (int v = t; v < npad; v += 256) {
        float4 w = (v < nv) ? sv4[v] : float4{0.f, 0.f, 0.f, 0.f};
        short4 o4;
        o4.x = f2bf(w.x * rinv);
        o4.y = f2bf(w.y * rinv);
        o4.z = f2bf(w.z * rinv);
        o4.w = f2bf(w.w * rinv);
        ((short4*)arow)[v] = o4;
    }
}

extern "C" void kernel_launch(void* const* d_in, const int* in_sizes, int n_in,
                              void* d_out, int out_size, void* d_ws, size_t ws_size,
                              hipStream_t stream) {
    const float* x  = (const float*)d_in[0];
    const float* wq = (const float*)d_in[1];
    const float* wk = (const float*)d_in[2];
    const float* wv = (const float*)d_in[3];
    float* out = (float*)d_out;

    // workspace layout (shorts)
    short* ws16 = (short*)d_ws;
    short* xb  = ws16;                 //  8,388,608
    short* wqb = xb + 8388608;         //  1,048,576  Wq bf16 row-major
    short* wkb = wqb + 1048576;        //  1,048,576  Wk bf16 row-major
    short* wtv = wkb + 1048576;        //  1,048,576  Wv^T bf16 [n][k]
    short* Mt  = wtv + 1048576;        //  1,048,576  (Wk Wq^T)/32 bf16
    short* tb  = Mt + 1048576;         //  8,388,608  t = x M bf16
    short* vt  = tb + 8388608;         //  8,388,608  V^T [4][1024][2048]
    float* scores = (float*)(vt + 8388608);  // 4*2048*2048 f32

    convx<<<8192, 256, 0, stream>>>(x, xb, 2097152);
    convx<<<1024, 256, 0, stream>>>(wq, wqb, 262144);
    convx<<<1024, 256, 0, stream>>>(wk, wkb, 262144);
    wtrans<<<dim3(16, 16, 1), 256, 0, stream>>>(wv, wtv);
    // Mt[m][n] = sum_e Wk[m][e] Wq[n][e] / 32  (= (Wq Wk^T)^T / 32)
    gemm128<5><<<64, 256, 0, stream>>>(
        wkb, 1024, 0LL, wqb, 1024, 0LL, Mt, 0.03125f,
        nullptr, nullptr, nullptr);
    // t[i][n] = sum_k x[i][k] Mt[n][k] = (x M)[i][n]
    gemm128<5><<<512, 256, 0, stream>>>(
        xb, 1024, 0LL, Mt, 1024, 0LL, tb, 1.0f,
        nullptr, nullptr, nullptr);
    // merged: scores[i][j] = sum_d t[i][d] x[j][d] (causal, 544 blocks)
    //         + vt = wtv @ xb^T (512 blocks)
    gemm128<1><<<1056, 256, 0, stream>>>(
        tb, 1024, 2097152LL, xb, 1024, 2097152LL, scores, 1.0f,
        wtv, xb, vt);
    softmax_causal<<<8192, 256, 0, stream>>>(scores);
    // out = attn @ vt^T, Kend = m0+128, paired block map
    gemm128<2><<<512, 256, 0, stream>>>(
        (const short*)scores, 4096, 8388608LL, vt, 2048, 2097152LL, out, 1.0f,
        nullptr, nullptr, nullptr);
}

// Round 10
// 164.056 us; speedup vs baseline: 1.4750x; 1.0449x over previous
//
#include <hip/hip_runtime.h>
#include <hip/hip_bf16.h>

// B=4, S=2048, D=1024. x:[4,2048,1024] f32; wq/wk/wv:[1024,1024] f32.
// out:[4,2048,1024] f32.
//
// R10 pipeline (bf16 MFMA, fp32 accum). scores = x (Wq Wk^T/32) x^T.
//   1. convall: x,wq,wk -> bf16 (one grid-stride kernel)
//   2. wtrans:  wv -> wtv bf16 transposed [1024(n)][1024(k)]
//   3. gemm128<5>: Mt = (wkb @ wqb^T)/32        [1024x1024] bf16
//   4. gemm128<5>: t  = xb @ Mt^T = x M         [8192x1024] bf16
//   5. gemm128<1>: MERGED: bid<544 live-triangular scores = t @ xb^T
//                  (bf16 out now); bid>=544 vt = wtv @ xb^T
//   6. softmax_wave: row-per-wave register softmax, bf16 in-place
//   7. gemm128<2>: out = attn @ vt^T, Kend=m0+128, paired block map
//
// GEMM core (R8 base + R10 micro-fix): 128^2 tile, BK=64, 4 waves, 64 KiB
// LDS dbuf (2 blocks/CU), 2-phase loop; NEW: all 16 ds_reads issued up
// front (group order pinned by sched_barrier(0)), counted lgkmcnt(8) for
// the k0 half, lgkmcnt(0) for k1 — one LDS-latency exposure per tile
// instead of two. Staging/swizzle/epilogue unchanged (0 conflicts).

typedef __attribute__((ext_vector_type(8))) short bf16x8;
typedef __attribute__((ext_vector_type(4))) float f32x4;

#define GLOAD_LDS16(g, l)                                                     \
    __builtin_amdgcn_global_load_lds(                                         \
        (const __attribute__((address_space(1))) void*)(g),                   \
        (__attribute__((address_space(3))) void*)(l), 16, 0, 0)

__device__ __forceinline__ short f2bf(float f) {
    union { float f; unsigned u; } v; v.f = f;
    unsigned r = v.u + 0x7FFFu + ((v.u >> 16) & 1u);
    return (short)(r >> 16);
}
__device__ __forceinline__ float bf2f(short h) {
    union { unsigned u; float f; } v;
    v.u = ((unsigned)(unsigned short)h) << 16;
    return v.f;
}

// ------- fused f32->bf16 converts: x (2M f4), wq (256K f4), wk (256K f4) ----
__global__ __launch_bounds__(256) void convall(
    const float* __restrict__ x, const float* __restrict__ wq,
    const float* __restrict__ wk, short* __restrict__ xb,
    short* __restrict__ wqb, short* __restrict__ wkb) {
    int i = blockIdx.x * 256 + threadIdx.x;  // 0..524287, grid 2048
#pragma unroll
    for (int s = 0; s < 5; ++s) {
        int v = i + s * 524288;              // < 2621440
        const float* src;
        short* dst;
        int off;
        if (v < 2097152)      { src = x;  dst = xb;  off = v; }
        else if (v < 2359296) { src = wq; dst = wqb; off = v - 2097152; }
        else                  { src = wk; dst = wkb; off = v - 2359296; }
        float4 w = ((const float4*)src)[off];
        short4 o;
        o.x = f2bf(w.x); o.y = f2bf(w.y); o.z = f2bf(w.z); o.w = f2bf(w.w);
        ((short4*)dst)[off] = o;
    }
}

// ---------------- wv: f32 [k][n] -> bf16 [n][k] ----------------
__global__ __launch_bounds__(256) void wtrans(const float* __restrict__ W,
                                              short* __restrict__ O) {
    int n0 = blockIdx.x * 64, k0 = blockIdx.y * 64;
    __shared__ float tile[64][65];
    int t = threadIdx.x;
#pragma unroll
    for (int i = 0; i < 16; ++i) {
        int idx = t + i * 256;
        int r = idx >> 6, c = idx & 63;
        tile[r][c] = W[(size_t)(k0 + r) * 1024 + n0 + c];
    }
    __syncthreads();
#pragma unroll
    for (int i = 0; i < 16; ++i) {
        int idx = t + i * 256;
        int r = idx >> 6, c = idx & 63;
        O[(size_t)(n0 + r) * 1024 + k0 + c] = f2bf(tile[c][r]);
    }
}

// ---------------- 128x128 NT GEMM, 2-phase, 2 blocks/CU ----------------
// C[m][n] = sum_k A[m][k] * B[n][k]
// MODE 5: plain bf16 out (ld 1024), *scale; grid = (M/128)*8
// MODE 1: merged, grid 1056: bid<544 scores (triangular, causal, BF16 out
//         ld 2048); bid>=544 VT (bf16 out [4][1024][2048])
// MODE 2: PV, grid 512, paired heavy/light decode; A bf16 lda=2048
template <int MODE>
__global__ __launch_bounds__(256, 2) void gemm128(
    const short* __restrict__ A0, int lda0, long long sA,
    const short* __restrict__ B0, int ldb0, long long sB,
    void* __restrict__ C0, float scale,
    const short* __restrict__ Av, const short* __restrict__ Bv,
    short* __restrict__ Cv) {

    int m0, n0, z = 0, lda = lda0, ldb = ldb0;
    const short* Ab;
    const short* Bb;
    bool isVT = false;

    if (MODE == 2) {
        // paired decode: slots i and i+256 carry mt and 15-mt (sum const)
        int i = blockIdx.x;            // 0..511
        int j = i & 255;
        int mt = (i < 256) ? (15 - (j >> 5)) : (j >> 5);
        z = (j >> 3) & 3;
        m0 = mt * 128;
        n0 = (j & 7) * 128;
        Ab = A0 + (size_t)z * sA;
        Bb = B0 + (size_t)z * sB;
    } else {
        // T1: XCD swizzle (grids are multiples of 8)
        const int nblk = gridDim.x;
        const int raw = blockIdx.x;
        int bid = (raw & 7) * (nblk >> 3) + (raw >> 3);
        if (MODE == 5) {
            m0 = (bid >> 3) * 128;
            n0 = (bid & 7) * 128;
            Ab = A0; Bb = B0;
        } else {  // MODE 1
            if (bid < 544) {
                z = bid / 136;
                int f = bid - z * 136;
                int mt = (int)((sqrtf(8.f * f + 1.f) - 1.f) * 0.5f);
                if (mt * (mt + 1) / 2 > f) --mt;
                if ((mt + 1) * (mt + 2) / 2 <= f) ++mt;
                int nt_ = f - mt * (mt + 1) / 2;   // nt_ <= mt (live)
                m0 = mt * 128; n0 = nt_ * 128;
                Ab = A0 + (size_t)z * sA;
                Bb = B0 + (size_t)z * sB;
            } else {
                isVT = true;
                int v = bid - 544;            // 0..511
                m0 = (v >> 6) * 128;          // M=1024
                n0 = (v & 63) * 128;          // N=8192
                Ab = Av; Bb = Bv; lda = 1024; ldb = 1024;
            }
        }
    }

    const int tid = threadIdx.x;
    const int lane = tid & 63;
    const int wid = tid >> 6;
    const int wm = wid >> 1, wn = wid & 1;  // 2x2 waves, wave tile 64x64

    __shared__ __align__(16) short As[2][8192];
    __shared__ __align__(16) short Bs[2][8192];

    f32x4 acc[4][4] = {};

    const int Kend = (MODE == 2) ? (m0 + 128) : 1024;
    const int nt = Kend >> 6;

    // staging: 8 thr/row x 16B, 4 row-passes; physical slot (tid&7) of row r
    // holds logical slot (tid&7)^(r&7): pre-swizzled source, linear dest.
    const int srow = tid >> 3;                  // 0..31
    const int sl = (tid & 7) ^ (srow & 7);
    const short* Agp = Ab + (size_t)(m0 + srow) * lda + sl * 8;
    const short* Bgp = Bb + (size_t)(n0 + srow) * ldb + sl * 8;

#define SA(kt, bf)                                                            \
    do {                                                                      \
        const int _k = (kt) << 6;                                             \
        GLOAD_LDS16(Agp + _k,                     &As[bf][tid * 8]);          \
        GLOAD_LDS16(Agp + _k + (size_t)32 * lda,  &As[bf][2048 + tid * 8]);   \
        GLOAD_LDS16(Agp + _k + (size_t)64 * lda,  &As[bf][4096 + tid * 8]);   \
        GLOAD_LDS16(Agp + _k + (size_t)96 * lda,  &As[bf][6144 + tid * 8]);   \
    } while (0)
#define SB(kt, bf)                                                            \
    do {                                                                      \
        const int _k = (kt) << 6;                                             \
        GLOAD_LDS16(Bgp + _k,                     &Bs[bf][tid * 8]);          \
        GLOAD_LDS16(Bgp + _k + (size_t)32 * ldb,  &Bs[bf][2048 + tid * 8]);   \
        GLOAD_LDS16(Bgp + _k + (size_t)64 * ldb,  &Bs[bf][4096 + tid * 8]);   \
        GLOAD_LDS16(Bgp + _k + (size_t)96 * ldb,  &Bs[bf][6144 + tid * 8]);   \
    } while (0)

    const int r = lane & 15;
    const int g = lane >> 4;

#define LDA4(dst, bf, kk)                                                     \
    _Pragma("unroll") for (int q = 0; q < 4; ++q) {                           \
        const int rr = wm * 64 + q * 16 + r;                                  \
        dst[q] = *(const bf16x8*)&As[bf][rr * 64 +                            \
                                         ((((kk)*4 + g) ^ (rr & 7))) * 8];    \
    }
#define LDB4(dst, bf, kk)                                                     \
    _Pragma("unroll") for (int q = 0; q < 4; ++q) {                           \
        const int rb = wn * 64 + q * 16 + r;                                  \
        dst[q] = *(const bf16x8*)&Bs[bf][rb * 64 +                            \
                                         ((((kk)*4 + g) ^ (rb & 7))) * 8];    \
    }
#define LGKM(n)                                                               \
    asm volatile("s_waitcnt lgkmcnt(" #n ")" ::: "memory");                   \
    __builtin_amdgcn_sched_barrier(0)
#define VM0() asm volatile("s_waitcnt vmcnt(0)" ::: "memory")
#define BAR() __builtin_amdgcn_s_barrier()
#define MF(ar, br)                                                            \
    _Pragma("unroll") for (int mi = 0; mi < 4; ++mi)                          \
        _Pragma("unroll") for (int ni = 0; ni < 4; ++ni)                      \
            acc[mi][ni] = __builtin_amdgcn_mfma_f32_16x16x32_bf16(            \
                ar[mi], br[ni], acc[mi][ni], 0, 0, 0);

    SA(0, 0); SB(0, 0);
    VM0();
    BAR();

    int buf = 0;
    for (int t = 0; t < nt - 1; ++t) {
        const int nb = buf ^ 1;
        SA(t + 1, nb); SB(t + 1, nb);
        bf16x8 a0[4], b0[4], a1[4], b1[4];
        // issue ALL 16 ds_reads; pin group order so lgkmcnt counts are valid
        LDA4(a0, buf, 0); LDB4(b0, buf, 0);
        __builtin_amdgcn_sched_barrier(0);
        LDA4(a1, buf, 1); LDB4(b1, buf, 1);
        LGKM(8);     // k0 fragments (first 8 in issue order) landed
        MF(a0, b0);  // k1 reads fly under these MFMAs
        LGKM(0);
        MF(a1, b1);
        VM0();       // tile t+1's 8 loads (issued one compute phase ago)
        BAR();
        buf = nb;
    }
    {   // last tile
        bf16x8 a0[4], b0[4], a1[4], b1[4];
        LDA4(a0, buf, 0); LDB4(b0, buf, 0);
        __builtin_amdgcn_sched_barrier(0);
        LDA4(a1, buf, 1); LDB4(b1, buf, 1);
        LGKM(8);
        MF(a0, b0);
        LGKM(0);
        MF(a1, b1);
    }

    // ---- C epilogue: C/D layout col=lane&15, row=(lane>>4)*4+reg
    const int r4 = (lane >> 4) * 4;
#pragma unroll
    for (int mi = 0; mi < 4; ++mi) {
#pragma unroll
        for (int ni = 0; ni < 4; ++ni) {
            int col = n0 + wn * 64 + ni * 16 + r;
#pragma unroll
            for (int i = 0; i < 4; ++i) {
                int rr = m0 + wm * 64 + mi * 16 + r4 + i;
                float v = acc[mi][ni][i];
                if (MODE == 5) {
                    ((short*)C0)[(size_t)rr * 1024 + col] = f2bf(v * scale);
                } else if (MODE == 1) {
                    if (isVT) {
                        Cv[(size_t)(col >> 11) * 2097152 +
                           (size_t)rr * 2048 + (col & 2047)] = f2bf(v);
                    } else if (col <= rr) {
                        // scores now bf16, ld 2048
                        ((short*)C0)[(size_t)z * 4194304 +
                                     (size_t)rr * 2048 + col] = f2bf(v);
                    }
                } else {
                    ((float*)C0)[(size_t)z * 2097152 +
                                 (size_t)rr * 1024 + col] = v;
                }
            }
        }
    }
#undef SA
#undef SB
#undef LDA4
#undef LDB4
#undef LGKM
#undef VM0
#undef BAR
#undef MF
}

// ------- causal softmax, row per wave, all-register, bf16 in/out -----------
// 4 rows per 256-thread block; strips of 512 cols (8 bf16 per lane),
// statically unrolled (rule #20: no dynamic reg-array indexing).
__global__ __launch_bounds__(256) void softmax_wave(short* __restrict__ scores) {
    int row = (blockIdx.x << 2) + (threadIdx.x >> 6);  // 0..8191
    int lane = threadIdx.x & 63;
    int b = row >> 11, i = row & 2047;
    short* srow = scores + ((size_t)(b << 11) + i) * 2048;
    int L = i + 1;
    int Lpad = (i | 127) + 1;   // PV read extent for this row's block

    float vals[32];
    float mx = -1e30f;
#pragma unroll
    for (int s = 0; s < 4; ++s) {
        if (s * 512 < Lpad) {   // wave-uniform branch
            int j0 = (s << 9) + (lane << 3);
            bf16x8 h = *(const bf16x8*)&srow[j0];
#pragma unroll
            for (int e = 0; e < 8; ++e) {
                float f = ((j0 + e) < L) ? bf2f(h[e]) : -1e30f;
                vals[s * 8 + e] = f;
                mx = fmaxf(mx, f);
            }
        }
    }
#pragma unroll
    for (int o = 32; o > 0; o >>= 1) mx = fmaxf(mx, __shfl_down(mx, o));
    mx = __shfl(mx, 0);

    float sum = 0.f;
#pragma unroll
    for (int s = 0; s < 4; ++s) {
        if (s * 512 < Lpad) {
#pragma unroll
            for (int e = 0; e < 8; ++e) {
                float ex = __expf(vals[s * 8 + e] - mx);  // masked -> 0
                vals[s * 8 + e] = ex;
                sum += ex;
            }
        }
    }
#pragma unroll
    for (int o = 32; o > 0; o >>= 1) sum += __shfl_down(sum, o);
    sum = __shfl(sum, 0);
    float rinv = 1.0f / sum;

#pragma unroll
    for (int s = 0; s < 4; ++s) {
        if (s * 512 < Lpad) {
            int j0 = (s << 9) + (lane << 3);
            bf16x8 o8;
#pragma unroll
            for (int e = 0; e < 8; ++e) o8[e] = f2bf(vals[s * 8 + e] * rinv);
            *(bf16x8*)&srow[j0] = o8;
        }
    }
}

extern "C" void kernel_launch(void* const* d_in, const int* in_sizes, int n_in,
                              void* d_out, int out_size, void* d_ws, size_t ws_size,
                              hipStream_t stream) {
    const float* x  = (const float*)d_in[0];
    const float* wq = (const float*)d_in[1];
    const float* wk = (const float*)d_in[2];
    const float* wv = (const float*)d_in[3];
    float* out = (float*)d_out;

    // workspace layout (shorts)
    short* ws16 = (short*)d_ws;
    short* xb  = ws16;                 //  8,388,608
    short* wqb = xb + 8388608;         //  1,048,576
    short* wkb = wqb + 1048576;        //  1,048,576
    short* wtv = wkb + 1048576;        //  1,048,576  Wv^T [n][k]
    short* Mt  = wtv + 1048576;        //  1,048,576  (Wk Wq^T)/32
    short* tb  = Mt + 1048576;         //  8,388,608  t = x M
    short* vt  = tb + 8388608;         //  8,388,608  V^T [4][1024][2048]
    short* scores = vt + 8388608;      // 16,777,216  bf16 [4][2048][2048]

    convall<<<2048, 256, 0, stream>>>(x, wq, wk, xb, wqb, wkb);
    wtrans<<<dim3(16, 16, 1), 256, 0, stream>>>(wv, wtv);
    // Mt[m][n] = sum_e Wk[m][e] Wq[n][e] / 32
    gemm128<5><<<64, 256, 0, stream>>>(
        wkb, 1024, 0LL, wqb, 1024, 0LL, Mt, 0.03125f,
        nullptr, nullptr, nullptr);
    // t[i][n] = sum_k x[i][k] Mt[n][k]
    gemm128<5><<<512, 256, 0, stream>>>(
        xb, 1024, 0LL, Mt, 1024, 0LL, tb, 1.0f,
        nullptr, nullptr, nullptr);
    // merged: scores (544 live triangular, bf16 out) + VT (512)
    gemm128<1><<<1056, 256, 0, stream>>>(
        tb, 1024, 2097152LL, xb, 1024, 2097152LL, scores, 1.0f,
        wtv, xb, vt);
    softmax_wave<<<2048, 256, 0, stream>>>(scores);
    // out = attn @ vt^T, Kend = m0+128, paired block map; attn lda=2048
    gemm128<2><<<512, 256, 0, stream>>>(
        scores, 2048, 4194304LL, vt, 2048, 2097152LL, out, 1.0f,
        nullptr, nullptr, nullptr);
}